// Round 6
// baseline (358.694 us; speedup 1.0000x reference)
//
#include <hip/hip_runtime.h>
#include <hip/hip_bf16.h>

typedef __hip_bfloat16 bf16;
typedef __attribute__((ext_vector_type(8))) short short8v;
typedef __attribute__((ext_vector_type(4))) float f32x4;

__device__ __forceinline__ float b2f(bf16 v){ return __bfloat162float(v); }
__device__ __forceinline__ bf16  f2b(float v){ return __float2bfloat16(v); }
__device__ __forceinline__ float su2f(short s){
    unsigned short us = (unsigned short)s;
    return __bfloat162float(*reinterpret_cast<bf16*>(&us));
}

constexpr int Bn = 8, CIN = 384, RESn = 28, Nn = 784, DHn = 1024;
constexpr int AST = 800;   // padded attn/vt K-stride (25*32)

// ---------------------------------------------------- async global->LDS 16B
__device__ __forceinline__ void gload16(const void* g, void* l)
{
    __builtin_amdgcn_global_load_lds(
        (const __attribute__((address_space(1))) void*)g,
        (__attribute__((address_space(3))) void*)l, 16, 0, 0);
}

// -------------------------------------------------- dtype detector (1 thread)
__global__ void k_detect(const unsigned* __restrict__ xw, int* __restrict__ flag)
{
    if (blockIdx.x == 0 && threadIdx.x == 0) {
        int cnt = 0;
        for (int i = 0; i < 256; ++i) {
            unsigned lo = xw[i] & 0xFFFFu;
            int e = (int)((lo >> 7) & 0xFF);
            if (e >= 112 && e <= 132) ++cnt;
        }
        *flag = (cnt >= 128) ? 1 : 0;
    }
}

// ------------------------------------- convert ALL input tensors -> bf16
struct ConvArgs { const void* src[26]; unsigned long long dstoff[26]; int n[26]; };
__global__ void k_convb_all(ConvArgs a, char* __restrict__ ws, const int* __restrict__ flag)
{
    int i = blockIdx.y;
    int n = a.n[i];
    const void* s = a.src[i];
    bf16* d = (bf16*)(ws + a.dstoff[i]);
    int isb = *flag;
    int stride = gridDim.x * blockDim.x;
    for (int t = blockIdx.x * blockDim.x + threadIdx.x; t < n; t += stride)
        d[t] = isb ? ((const bf16*)s)[t] : f2b(((const float*)s)[t]);
}

// ---------------------------------------------------------------- mixed bias
__global__ void k_mixbias(const bf16* __restrict__ ab, const bf16* __restrict__ W1,
                          const bf16* __restrict__ b1, float* __restrict__ mb)
{
    int i = blockIdx.x * 256 + threadIdx.x;
    if (i >= 8 * Nn) return;
    int g = i / Nn, p = i % Nn;
    float acc = b2f(b1[g]);
    for (int h = 0; h < 8; ++h) acc += b2f(W1[g * 8 + h]) * b2f(ab[h * Nn + p]);
    mb[g * Nn + p] = acc;
}

// ------------------- expand mb through idx: abfull[g][n][m] (b-independent)
__global__ __launch_bounds__(256) void k_abfull(
    const float* __restrict__ mb, const int* __restrict__ idxs,
    bf16* __restrict__ abfull)
{
    __shared__ float mbs[8][Nn];
    const int tid = threadIdx.x;
    for (int i = tid; i < 8 * Nn; i += 256) ((float*)mbs)[i] = mb[i];
    __syncthreads();
    const int nstart = blockIdx.x * 14;
    for (int n = nstart; n < nstart + 14; ++n) {
        for (int m = tid; m < Nn; m += 256) {
            int id = idxs[(size_t)n * Nn + m];
            #pragma unroll
            for (int g = 0; g < 8; ++g)
                abfull[((size_t)g * Nn + n) * AST + m] = f2b(mbs[g][id]);
        }
    }
}

// ----------------------------------------- pack Wq|Wk|Wv -> Wqkv [1536][384]
__global__ void k_wpack(const bf16* __restrict__ Wq, const bf16* __restrict__ Wk,
                        const bf16* __restrict__ Wv, bf16* __restrict__ Wqkv)
{
    int t = blockIdx.x * 256 + threadIdx.x;
    if (t >= 1536 * 48) return;
    int co = t / 48, j = t % 48;
    const bf16* src = (co < 256) ? Wq + (size_t)co * 384
                    : (co < 512) ? Wk + (size_t)(co - 256) * 384
                                 : Wv + (size_t)(co - 512) * 384;
    ((short8v*)Wqkv)[t] = ((const short8v*)src)[j];
}

// ------------------------------------------------- affine (alpha,beta)[1536]
__global__ void k_affine(const bf16* bq, const bf16* qs, const bf16* qb,
                         const bf16* bk, const bf16* ks, const bf16* kb,
                         const bf16* bv, const bf16* vs, const bf16* vb,
                         float* __restrict__ al, float* __restrict__ be)
{
    int co = blockIdx.x * 256 + threadIdx.x;
    if (co >= 1536) return;
    const bf16 *b_, *s_, *h_; int lc;
    if (co < 256)      { b_ = bq; s_ = qs; h_ = qb; lc = co; }
    else if (co < 512) { b_ = bk; s_ = ks; h_ = kb; lc = co - 256; }
    else               { b_ = bv; s_ = vs; h_ = vb; lc = co - 512; }
    float a = b2f(s_[lc]);
    al[co] = a;
    be[co] = b2f(b_[lc]) * a + b2f(h_[lc]);
}

// --------------------------------- x transpose: [b][384][784] -> [b][784][384]
__global__ __launch_bounds__(256) void k_xt(const bf16* __restrict__ x, bf16* __restrict__ xt)
{
    __shared__ bf16 t[32][33];
    int b = blockIdx.z, n0 = blockIdx.x * 32, c0 = blockIdx.y * 32;
    int tid = threadIdx.x;
    for (int i = tid; i < 1024; i += 256) {
        int r = i >> 5, c = i & 31;
        int n = n0 + c;
        t[r][c] = (n < Nn) ? x[((size_t)b * CIN + c0 + r) * Nn + n] : f2b(0.f);
    }
    __syncthreads();
    for (int i = tid; i < 1024; i += 256) {
        int r = i >> 5, c = i & 31;
        int n = n0 + r;
        if (n < Nn) xt[((size_t)b * Nn + n) * CIN + c0 + c] = t[c][r];
    }
}

// --------------------- v transpose: [n][c] -> [c][n] (stride AST, zero-padded)
__global__ __launch_bounds__(256) void k_vt(const bf16* __restrict__ vbuf, bf16* __restrict__ vt)
{
    __shared__ bf16 t[32][33];
    int b = blockIdx.z, n0 = blockIdx.x * 32, c0 = blockIdx.y * 32;
    int tid = threadIdx.x;
    for (int i = tid; i < 1024; i += 256) {
        int r = i >> 5, c = i & 31;
        int n = n0 + r;
        t[r][c] = (n < Nn) ? vbuf[((size_t)b * Nn + n) * DHn + c0 + c] : f2b(0.f);
    }
    __syncthreads();
    for (int i = tid; i < 1024; i += 256) {
        int r = i >> 5, c = i & 31;
        int n = n0 + c;   // n < 800 always (25*32 grid)
        vt[((size_t)b * DHn + c0 + r) * AST + n] = t[c][r];
    }
}

// ------------------- generic MFMA core: tile (MI*32) x 128, BK=32, gload_lds
template<int MI>
__device__ __forceinline__ void gemm_core(
    const bf16* __restrict__ A, int lda, int rowsA, int arow0,
    const bf16* __restrict__ B, int ldb, int rowsB, int brow0,
    int K, short* ldsA, short* ldsB, f32x4 (&acc)[MI][4])
{
    const int tid  = threadIdx.x;
    const int lane = tid & 63;
    const int wm   = tid >> 7, wn = (tid >> 6) & 1;
    const int rsub = ((tid >> 6) << 4) | (tid & 15);
    const int q    = (tid >> 4) & 3;
    const int wbase = tid & 192;
    const short8v* A8 = (const short8v*)ldsA;
    const short8v* B8 = (const short8v*)ldsB;

    for (int k0 = 0; k0 < K; k0 += 32) {
        __syncthreads();
        #pragma unroll
        for (int c = 0; c < MI / 2; ++c) {
            int row = arow0 + c * 64 + rsub; row = row < rowsA ? row : rowsA - 1;
            gload16((const short*)A + (size_t)row * lda + k0 + q * 8,
                    ldsA + (size_t)(c * 256 + wbase) * 8);
        }
        #pragma unroll
        for (int c = 0; c < 2; ++c) {
            int row = brow0 + c * 64 + rsub; row = row < rowsB ? row : rowsB - 1;
            gload16((const short*)B + (size_t)row * ldb + k0 + q * 8,
                    ldsB + (size_t)(c * 256 + wbase) * 8);
        }
        __syncthreads();
        short8v a[MI], bb[4];
        #pragma unroll
        for (int i = 0; i < MI; ++i) a[i] = A8[(wm * MI + i) * 64 + lane];
        #pragma unroll
        for (int j = 0; j < 4; ++j) bb[j] = B8[(wn * 4 + j) * 64 + lane];
        #pragma unroll
        for (int i = 0; i < MI; ++i)
            #pragma unroll
            for (int j = 0; j < 4; ++j)
                acc[i][j] = __builtin_amdgcn_mfma_f32_16x16x32_bf16(a[i], bb[j], acc[i][j], 0, 0, 0);
    }
}

#define EPI_COORDS(MI)                                      \
    const int tid  = threadIdx.x;                           \
    const int lane = tid & 63;                              \
    const int wm   = tid >> 7, wn = (tid >> 6) & 1;         \
    const int rq   = lane >> 4, cl = lane & 15; (void)rq;

// --------------------------------------------- q/k/v projection + BN (MFMA)
__global__ __launch_bounds__(256) void k_proj_m(
    const bf16* __restrict__ xt, const bf16* __restrict__ Wqkv,
    const float* __restrict__ al, const float* __restrict__ be,
    bf16* __restrict__ qbuf, bf16* __restrict__ kbuf, bf16* __restrict__ vbuf)
{
    __shared__ short ldsA[4096], ldsB[4096];
    const int n0 = blockIdx.x * 128, co0 = blockIdx.y * 128;
    const int b = blockIdx.z;
    f32x4 acc[4][4] = {};
    gemm_core<4>(xt + (size_t)b * Nn * CIN, CIN, Nn, n0,
                 Wqkv, CIN, 1536, co0, CIN, ldsA, ldsB, acc);
    EPI_COORDS(4)
    #pragma unroll
    for (int i = 0; i < 4; ++i)
        #pragma unroll
        for (int j = 0; j < 4; ++j) {
            int co = co0 + (wn * 4 + j) * 16 + cl;
            float a_ = al[co], bb_ = be[co];
            int nb = n0 + (wm * 4 + i) * 16 + rq * 4;
            #pragma unroll
            for (int r = 0; r < 4; ++r) {
                int n = nb + r;
                if (n >= Nn) continue;
                float y = a_ * acc[i][j][r] + bb_;
                if (co < 256)      qbuf[((size_t)b * Nn + n) * 256 + co]       = f2b(y);
                else if (co < 512) kbuf[((size_t)b * Nn + n) * 256 + (co-256)] = f2b(y);
                else               vbuf[((size_t)b * Nn + n) * DHn + (co-512)] = f2b(y);
            }
        }
}

// ----------------------- raw per-head logits: qk[h][n][m], K=32 (no mix/bias)
__global__ __launch_bounds__(256) void k_logits_raw(
    const bf16* __restrict__ qbuf, const bf16* __restrict__ kbuf,
    bf16* __restrict__ attn, int bi0)
{
    __shared__ short ldsA[4096], ldsB[4096];
    const int n0 = blockIdx.x * 128, m0 = blockIdx.y * 128;
    const int z = blockIdx.z, h = z & 7, bloc = z >> 3, b = bi0 + bloc;
    f32x4 acc[4][4] = {};
    gemm_core<4>(qbuf + (size_t)b * Nn * 256 + h * 32, 256, Nn, n0,
                 kbuf + (size_t)b * Nn * 256 + h * 32, 256, Nn, m0,
                 32, ldsA, ldsB, acc);
    bf16* arow = attn + (size_t)(bloc * 8 + h) * Nn * AST;
    EPI_COORDS(4)
    #pragma unroll
    for (int i = 0; i < 4; ++i)
        #pragma unroll
        for (int j = 0; j < 4; ++j) {
            int m = m0 + (wn * 4 + j) * 16 + cl;
            if (m >= Nn) continue;
            int nb = n0 + (wm * 4 + i) * 16 + rq * 4;
            #pragma unroll
            for (int r = 0; r < 4; ++r) {
                int n = nb + r;
                if (n < Nn) arow[(size_t)n * AST + m] = f2b(acc[i][j][r]);
            }
        }
}

// --- fused: th1 mix (+abfull bias) + softmax + th2 mix, in-place, padded attn
__global__ __launch_bounds__(256) void k_softmax_mix(
    bf16* __restrict__ attn_all, const bf16* __restrict__ abfull,
    const bf16* __restrict__ W1, const bf16* __restrict__ W2, const bf16* __restrict__ b2v)
{
    const int n = blockIdx.x, bloc = blockIdx.y;
    const int tid = threadIdx.x;
    bf16* base = attn_all + (size_t)bloc * 8 * Nn * AST;
    __shared__ float e[8][801];
    __shared__ float w1s[64], w2s[64], b2sh[8], mxs[8], lis[8], wred[4][8];

    if (tid < 64) { w1s[tid] = b2f(W1[tid]) * 0.17677669529663687f; w2s[tid] = b2f(W2[tid]); }
    if (tid < 8) b2sh[tid] = b2f(b2v[tid]);

    const int grp = tid >> 5, gl = tid & 31;
    {
        const bf16* row = base + ((size_t)grp * Nn + n) * AST;
        for (int j = gl; j < 98; j += 32) {
            short8v v = ((const short8v*)row)[j];
            #pragma unroll
            for (int u = 0; u < 8; ++u) e[grp][j * 8 + u] = su2f(v[u]);
        }
    }
    __syncthreads();

    const bf16* abn = abfull + (size_t)n * AST;   // + g*Nn*AST + m
    float mx8[8];
    #pragma unroll
    for (int g = 0; g < 8; ++g) mx8[g] = -1e30f;
    for (int m = tid; m < Nn; m += 256) {
        float raw[8];
        #pragma unroll
        for (int h = 0; h < 8; ++h) raw[h] = e[h][m];
        float out[8];
        #pragma unroll
        for (int g = 0; g < 8; ++g) {
            float a = su2f(*(const short*)&abn[(size_t)g * Nn * AST + m]);
            #pragma unroll
            for (int h = 0; h < 8; ++h) a += w1s[g * 8 + h] * raw[h];
            out[g] = a;
            mx8[g] = fmaxf(mx8[g], a);
        }
        #pragma unroll
        for (int g = 0; g < 8; ++g) e[g][m] = out[g];
    }
    #pragma unroll
    for (int g = 0; g < 8; ++g) {
        float v = mx8[g];
        #pragma unroll
        for (int s = 32; s > 0; s >>= 1) v = fmaxf(v, __shfl_xor(v, s, 64));
        if ((tid & 63) == 0) wred[tid >> 6][g] = v;
    }
    __syncthreads();
    if (tid < 8)
        mxs[tid] = fmaxf(fmaxf(wred[0][tid], wred[1][tid]), fmaxf(wred[2][tid], wred[3][tid]));
    __syncthreads();

    float s8[8];
    #pragma unroll
    for (int g = 0; g < 8; ++g) s8[g] = 0.f;
    for (int m = tid; m < Nn; m += 256) {
        #pragma unroll
        for (int g = 0; g < 8; ++g) {
            float ev = __expf(e[g][m] - mxs[g]);
            e[g][m] = ev;
            s8[g] += ev;
        }
    }
    #pragma unroll
    for (int g = 0; g < 8; ++g) {
        float v = s8[g];
        #pragma unroll
        for (int s = 32; s > 0; s >>= 1) v += __shfl_xor(v, s, 64);
        if ((tid & 63) == 0) wred[tid >> 6][g] = v;
    }
    __syncthreads();
    if (tid < 8)
        lis[tid] = 1.f / (wred[0][tid] + wred[1][tid] + wred[2][tid] + wred[3][tid]);
    __syncthreads();

    float li[8];
    #pragma unroll
    for (int h = 0; h < 8; ++h) li[h] = lis[h];
    for (int m = tid; m < Nn; m += 256) {
        float eh[8];
        #pragma unroll
        for (int h = 0; h < 8; ++h) eh[h] = e[h][m] * li[h];
        #pragma unroll
        for (int g = 0; g < 8; ++g) {
            float a = b2sh[g];
            #pragma unroll
            for (int h = 0; h < 8; ++h) a += w2s[g * 8 + h] * eh[h];
            base[((size_t)g * Nn + n) * AST + m] = f2b(a);
        }
    }
    if (tid < 128) {
        int g = tid >> 4, mp = Nn + (tid & 15);
        base[((size_t)g * Nn + n) * AST + mp] = f2b(0.f);
    }
}

// ------------------------------------------------ PV: obuf[b][n][c] = P2 · v
__global__ __launch_bounds__(256) void k_pv_m(
    const bf16* __restrict__ attn, const bf16* __restrict__ vt,
    bf16* __restrict__ obuf, int bi0)
{
    __shared__ short ldsA[4096], ldsB[4096];
    const int n0 = blockIdx.x * 128;
    const int z = blockIdx.z, g = z & 7, bloc = z >> 3, b = bi0 + bloc;
    f32x4 acc[4][4] = {};
    gemm_core<4>(attn + (size_t)(bloc * 8 + g) * Nn * AST, AST, Nn, n0,
                 vt + ((size_t)b * DHn + g * 128) * AST, AST, 128, 0,
                 AST, ldsA, ldsB, acc);
    bf16* ob = obuf + (size_t)b * Nn * DHn + g * 128;
    EPI_COORDS(4)
    #pragma unroll
    for (int i = 0; i < 4; ++i)
        #pragma unroll
        for (int j = 0; j < 4; ++j) {
            int d = (wn * 4 + j) * 16 + cl;
            int nb = n0 + (wm * 4 + i) * 16 + rq * 4;
            #pragma unroll
            for (int r = 0; r < 4; ++r) {
                int n = nb + r;
                if (n < Nn) ob[(size_t)n * DHn + d] = f2b(acc[i][j][r]);
            }
        }
}

// ------------------- depthwise conv+BN, ADDS into obuf (o += vl), vectorized
__global__ __launch_bounds__(256) void k_dwconv_add(
    const bf16* __restrict__ vbuf, const bf16* __restrict__ Wvl,
    const bf16* __restrict__ bvl, const bf16* __restrict__ vls, const bf16* __restrict__ vlb,
    bf16* __restrict__ obuf)
{
    const int t = threadIdx.x;
    const int n = blockIdx.y * 2 + (t >> 7);
    const int bi = blockIdx.z;
    const int c0 = (t & 127) * 8;
    const int h = n / RESn, w = n % RESn;
    float acc[8] = {};
    #pragma unroll
    for (int dh = -1; dh <= 1; ++dh)
        #pragma unroll
        for (int dw = -1; dw <= 1; ++dw) {
            int hh = h + dh, ww = w + dw;
            if (hh < 0 || hh >= RESn || ww < 0 || ww >= RESn) continue;
            short8v v = *(const short8v*)&vbuf[((size_t)bi * Nn + hh * RESn + ww) * DHn + c0];
            int widx = (dh + 1) * 3 + (dw + 1);
            #pragma unroll
            for (int u = 0; u < 8; ++u)
                acc[u] += b2f(Wvl[(size_t)(c0 + u) * 9 + widx]) * su2f(v[u]);
        }
    size_t off = ((size_t)bi * Nn + n) * DHn + c0;
    short8v ov = *(short8v*)&obuf[off];
    short8v res;
    #pragma unroll
    for (int u = 0; u < 8; ++u) {
        float s = b2f(vls[c0 + u]);
        float vl = s * (acc[u] + b2f(bvl[c0 + u])) + b2f(vlb[c0 + u]);
        bf16 bo = f2b(su2f(ov[u]) + vl);
        res[u] = *reinterpret_cast<short*>(&bo);
    }
    *(short8v*)&obuf[off] = res;
}

// --------------------------------------------- output projection + BN (MFMA)
__global__ __launch_bounds__(256) void k_outproj_m(
    const bf16* __restrict__ Wp, const bf16* __restrict__ obuf,
    const bf16* __restrict__ bp, const bf16* __restrict__ ps, const bf16* __restrict__ pb,
    void* __restrict__ outv, const int* __restrict__ flag)
{
    __shared__ short ldsA[2048], ldsB[4096];
    const int n0 = blockIdx.x * 128, oc0 = blockIdx.y * 64;
    const int b = blockIdx.z;
    f32x4 acc[2][4] = {};
    gemm_core<2>(Wp, DHn, 384, oc0,
                 obuf + (size_t)b * Nn * DHn, DHn, Nn, n0,
                 DHn, ldsA, ldsB, acc);
    const int isb = *flag;
    EPI_COORDS(2)
    #pragma unroll
    for (int i = 0; i < 2; ++i)
        #pragma unroll
        for (int j = 0; j < 4; ++j) {
            int n = n0 + (wn * 4 + j) * 16 + cl;
            if (n >= Nn) continue;
            int ocb = oc0 + (wm * 2 + i) * 16 + rq * 4;
            #pragma unroll
            for (int r = 0; r < 4; ++r) {
                int oc = ocb + r;
                float a_ = b2f(ps[oc]);
                float be_ = b2f(bp[oc]) * a_ + b2f(pb[oc]);
                float y = a_ * acc[i][j][r] + be_;
                size_t idx = ((size_t)b * CIN + oc) * Nn + n;
                if (isb) ((bf16*)outv)[idx] = f2b(y);
                else     ((float*)outv)[idx] = y;
            }
        }
}

extern "C" void kernel_launch(void* const* d_in, const int* in_sizes, int n_in,
                              void* d_out, int out_size, void* d_ws, size_t ws_size,
                              hipStream_t stream)
{
    char* ws = (char*)d_ws;
    auto align256 = [](size_t v) { return (v + 255) & ~(size_t)255; };

    size_t off = 0;
    size_t off_flag = off;            off = align256(off + 4);
    size_t p_off[26];
    for (int i = 0; i < 26; ++i) { p_off[i] = off; off = align256(off + (size_t)in_sizes[i] * 2); }
    size_t off_mb   = off; off = align256(off + (size_t)8 * Nn * 4);
    size_t off_ab   = off; off = align256(off + (size_t)8 * Nn * AST * 2);
    size_t off_q    = off; off = align256(off + (size_t)Bn * Nn * 256 * 2);
    size_t off_k    = off; off = align256(off + (size_t)Bn * Nn * 256 * 2);
    size_t off_v    = off; off = align256(off + (size_t)Bn * Nn * DHn * 2);
    size_t off_vt   = off; off = align256(off + (size_t)Bn * DHn * AST * 2);
    size_t off_o    = off; off = align256(off + (size_t)Bn * Nn * DHn * 2);
    size_t off_xt   = off; off = align256(off + (size_t)Bn * Nn * CIN * 2);
    size_t off_wqkv = off; off = align256(off + (size_t)1536 * CIN * 2);
    size_t off_al   = off; off = align256(off + (size_t)1536 * 4);
    size_t off_be   = off; off = align256(off + (size_t)1536 * 4);
    size_t base = off;

    const size_t attn_per_b = (size_t)8 * Nn * AST * 2;
    int GB = 0;
    const int cand[4] = {8, 4, 2, 1};
    for (int ci = 0; ci < 4; ++ci) {
        if (base + (size_t)cand[ci] * attn_per_b + 512 <= ws_size) { GB = cand[ci]; break; }
    }
    if (!GB) return; // ws too small -> zeros out (diagnostic absmax ~17.4)

    size_t off_attn = base;

    int*  flag = (int*)(ws + off_flag);
    bf16* Pb[26];
    for (int i = 0; i < 26; ++i) Pb[i] = (bf16*)(ws + p_off[i]);
    float* mb    = (float*)(ws + off_mb);
    bf16* abfull = (bf16*)(ws + off_ab);
    bf16* qbuf  = (bf16*)(ws + off_q);
    bf16* kbuf  = (bf16*)(ws + off_k);
    bf16* vbuf  = (bf16*)(ws + off_v);
    bf16* vt    = (bf16*)(ws + off_vt);
    bf16* obuf  = (bf16*)(ws + off_o);
    bf16* xt    = (bf16*)(ws + off_xt);
    bf16* wqkv  = (bf16*)(ws + off_wqkv);
    float* alf  = (float*)(ws + off_al);
    float* bef  = (float*)(ws + off_be);
    bf16* attn  = (bf16*)(ws + off_attn);
    const int* idxs = (const int*)d_in[26];

    k_detect<<<1, 64, 0, stream>>>((const unsigned*)d_in[0], flag);

    ConvArgs ca;
    for (int i = 0; i < 26; ++i) { ca.src[i] = d_in[i]; ca.dstoff[i] = p_off[i]; ca.n[i] = in_sizes[i]; }
    k_convb_all<<<dim3(128, 26), 256, 0, stream>>>(ca, ws, flag);

    bf16 *x = Pb[0], *Wq = Pb[1], *bq = Pb[2], *qs = Pb[3], *qb = Pb[4],
         *Wk = Pb[5], *bk = Pb[6], *ks = Pb[7], *kb = Pb[8],
         *Wv = Pb[9], *bv = Pb[10], *vs = Pb[11], *vb = Pb[12],
         *Wvl = Pb[13], *bvl = Pb[14], *vls = Pb[15], *vlb = Pb[16],
         *W1 = Pb[17], *b1 = Pb[18], *W2 = Pb[19], *b2v = Pb[20],
         *Wp = Pb[21], *bp = Pb[22], *ps = Pb[23], *pb = Pb[24], *ab = Pb[25];

    k_wpack<<<dim3((1536 * 48 + 255) / 256), 256, 0, stream>>>(Wq, Wk, Wv, wqkv);
    k_affine<<<dim3(6), 256, 0, stream>>>(bq, qs, qb, bk, ks, kb, bv, vs, vb, alf, bef);
    k_mixbias<<<dim3((8 * Nn + 255) / 256), 256, 0, stream>>>(ab, W1, b1, mb);
    k_abfull<<<dim3(56), 256, 0, stream>>>(mb, idxs, abfull);
    k_xt<<<dim3(25, 12, 8), 256, 0, stream>>>(x, xt);

    k_proj_m<<<dim3(7, 12, 8), 256, 0, stream>>>(xt, wqkv, alf, bef, qbuf, kbuf, vbuf);
    k_vt<<<dim3(25, 32, 8), 256, 0, stream>>>(vbuf, vt);

    for (int bi0 = 0; bi0 < Bn; bi0 += GB) {
        k_logits_raw<<<dim3(7, 7, GB * 8), 256, 0, stream>>>(qbuf, kbuf, attn, bi0);
        k_softmax_mix<<<dim3(Nn, GB), 256, 0, stream>>>(attn, abfull, W1, W2, b2v);
        k_pv_m<<<dim3(7, 1, GB * 8), 256, 0, stream>>>(attn, vt, obuf, bi0);
    }

    k_dwconv_add<<<dim3(1, Nn / 2, 8), 256, 0, stream>>>(vbuf, Wvl, bvl, vls, vlb, obuf);
    k_outproj_m<<<dim3(7, 6, 8), 256, 0, stream>>>(Wp, obuf, bp, ps, pb, d_out, flag);
}

// Round 7
// 294.642 us; speedup vs baseline: 1.2174x; 1.2174x over previous
//
#include <hip/hip_runtime.h>
#include <hip/hip_bf16.h>

typedef __hip_bfloat16 bf16;
typedef __attribute__((ext_vector_type(8))) short short8v;
typedef __attribute__((ext_vector_type(4))) short short4v;
typedef __attribute__((ext_vector_type(4))) float f32x4;

__device__ __forceinline__ float b2f(bf16 v){ return __bfloat162float(v); }
__device__ __forceinline__ bf16  f2b(float v){ return __float2bfloat16(v); }
__device__ __forceinline__ float su2f(short s){
    unsigned short us = (unsigned short)s;
    return __bfloat162float(*reinterpret_cast<bf16*>(&us));
}

constexpr int Bn = 8, CIN = 384, RESn = 28, Nn = 784, DHn = 1024;
constexpr int AST = 800;   // padded attn/vt K-stride (25*32)

// ---------------------------------------------------- async global->LDS 16B
__device__ __forceinline__ void gload16(const void* g, void* l)
{
    __builtin_amdgcn_global_load_lds(
        (const __attribute__((address_space(1))) void*)g,
        (__attribute__((address_space(3))) void*)l, 16, 0, 0);
}

// -------------------------------------------------- dtype detector (1 thread)
__global__ void k_detect(const unsigned* __restrict__ xw, int* __restrict__ flag)
{
    if (blockIdx.x == 0 && threadIdx.x == 0) {
        int cnt = 0;
        for (int i = 0; i < 256; ++i) {
            unsigned lo = xw[i] & 0xFFFFu;
            int e = (int)((lo >> 7) & 0xFF);
            if (e >= 112 && e <= 132) ++cnt;
        }
        *flag = (cnt >= 128) ? 1 : 0;
    }
}

// ------------------------------------- convert ALL input tensors -> bf16
struct ConvArgs { const void* src[26]; unsigned long long dstoff[26]; int n[26]; };
__global__ void k_convb_all(ConvArgs a, char* __restrict__ ws, const int* __restrict__ flag)
{
    int i = blockIdx.y;
    int n = a.n[i];
    const void* s = a.src[i];
    bf16* d = (bf16*)(ws + a.dstoff[i]);
    int isb = *flag;
    int stride = gridDim.x * blockDim.x;
    for (int t = blockIdx.x * blockDim.x + threadIdx.x; t < n; t += stride)
        d[t] = isb ? ((const bf16*)s)[t] : f2b(((const float*)s)[t]);
}

// ---------------------------------------------------------------- mixed bias
__global__ void k_mixbias(const bf16* __restrict__ ab, const bf16* __restrict__ W1,
                          const bf16* __restrict__ b1, float* __restrict__ mb)
{
    int i = blockIdx.x * 256 + threadIdx.x;
    if (i >= 8 * Nn) return;
    int g = i / Nn, p = i % Nn;
    float acc = b2f(b1[g]);
    for (int h = 0; h < 8; ++h) acc += b2f(W1[g * 8 + h]) * b2f(ab[h * Nn + p]);
    mb[g * Nn + p] = acc;
}

// ------------------- expand mb through idx: abfull[g][n][m] (b-independent)
__global__ __launch_bounds__(256) void k_abfull(
    const float* __restrict__ mb, const int* __restrict__ idxs,
    bf16* __restrict__ abfull)
{
    __shared__ float mbs[8][Nn];
    const int tid = threadIdx.x;
    for (int i = tid; i < 8 * Nn; i += 256) ((float*)mbs)[i] = mb[i];
    __syncthreads();
    const int nstart = blockIdx.x * 2;
    for (int n = nstart; n < nstart + 2; ++n) {
        for (int m = tid; m < Nn; m += 256) {
            int id = idxs[(size_t)n * Nn + m];
            #pragma unroll
            for (int g = 0; g < 8; ++g)
                abfull[((size_t)g * Nn + n) * AST + m] = f2b(mbs[g][id]);
        }
    }
}

// ----------------------------------------- pack Wq|Wk|Wv -> Wqkv [1536][384]
__global__ void k_wpack(const bf16* __restrict__ Wq, const bf16* __restrict__ Wk,
                        const bf16* __restrict__ Wv, bf16* __restrict__ Wqkv)
{
    int t = blockIdx.x * 256 + threadIdx.x;
    if (t >= 1536 * 48) return;
    int co = t / 48, j = t % 48;
    const bf16* src = (co < 256) ? Wq + (size_t)co * 384
                    : (co < 512) ? Wk + (size_t)(co - 256) * 384
                                 : Wv + (size_t)(co - 512) * 384;
    ((short8v*)Wqkv)[t] = ((const short8v*)src)[j];
}

// ------------------------------------------------- affine (alpha,beta)[1536]
__global__ void k_affine(const bf16* bq, const bf16* qs, const bf16* qb,
                         const bf16* bk, const bf16* ks, const bf16* kb,
                         const bf16* bv, const bf16* vs, const bf16* vb,
                         float* __restrict__ al, float* __restrict__ be)
{
    int co = blockIdx.x * 256 + threadIdx.x;
    if (co >= 1536) return;
    const bf16 *b_, *s_, *h_; int lc;
    if (co < 256)      { b_ = bq; s_ = qs; h_ = qb; lc = co; }
    else if (co < 512) { b_ = bk; s_ = ks; h_ = kb; lc = co - 256; }
    else               { b_ = bv; s_ = vs; h_ = vb; lc = co - 512; }
    float a = b2f(s_[lc]);
    al[co] = a;
    be[co] = b2f(b_[lc]) * a + b2f(h_[lc]);
}

// --------------------------------- x transpose: [b][384][784] -> [b][784][384]
__global__ __launch_bounds__(256) void k_xt(const bf16* __restrict__ x, bf16* __restrict__ xt)
{
    __shared__ bf16 t[32][33];
    int b = blockIdx.z, n0 = blockIdx.x * 32, c0 = blockIdx.y * 32;
    int tid = threadIdx.x;
    for (int i = tid; i < 1024; i += 256) {
        int r = i >> 5, c = i & 31;
        int n = n0 + c;
        t[r][c] = (n < Nn) ? x[((size_t)b * CIN + c0 + r) * Nn + n] : f2b(0.f);
    }
    __syncthreads();
    for (int i = tid; i < 1024; i += 256) {
        int r = i >> 5, c = i & 31;
        int n = n0 + r;
        if (n < Nn) xt[((size_t)b * Nn + n) * CIN + c0 + c] = t[c][r];
    }
}

// --------------------- v transpose: [n][c] -> [c][n] (stride AST, zero-padded)
__global__ __launch_bounds__(256) void k_vt(const bf16* __restrict__ vbuf, bf16* __restrict__ vt)
{
    __shared__ bf16 t[32][33];
    int b = blockIdx.z, n0 = blockIdx.x * 32, c0 = blockIdx.y * 32;
    int tid = threadIdx.x;
    for (int i = tid; i < 1024; i += 256) {
        int r = i >> 5, c = i & 31;
        int n = n0 + r;
        t[r][c] = (n < Nn) ? vbuf[((size_t)b * Nn + n) * DHn + c0 + c] : f2b(0.f);
    }
    __syncthreads();
    for (int i = tid; i < 1024; i += 256) {
        int r = i >> 5, c = i & 31;
        int n = n0 + c;   // n < 800 always (25*32 grid)
        vt[((size_t)b * DHn + c0 + r) * AST + n] = t[c][r];
    }
}

// ------------------- generic MFMA core: tile (MI*32) x 128, BK=32, gload_lds
template<int MI>
__device__ __forceinline__ void gemm_core(
    const bf16* __restrict__ A, int lda, int rowsA, int arow0,
    const bf16* __restrict__ B, int ldb, int rowsB, int brow0,
    int K, short* ldsA, short* ldsB, f32x4 (&acc)[MI][4])
{
    const int tid  = threadIdx.x;
    const int lane = tid & 63;
    const int wm   = tid >> 7, wn = (tid >> 6) & 1;
    const int rsub = ((tid >> 6) << 4) | (tid & 15);
    const int q    = (tid >> 4) & 3;
    const int wbase = tid & 192;
    const short8v* A8 = (const short8v*)ldsA;
    const short8v* B8 = (const short8v*)ldsB;

    for (int k0 = 0; k0 < K; k0 += 32) {
        __syncthreads();
        #pragma unroll
        for (int c = 0; c < MI / 2; ++c) {
            int row = arow0 + c * 64 + rsub; row = row < rowsA ? row : rowsA - 1;
            gload16((const short*)A + (size_t)row * lda + k0 + q * 8,
                    ldsA + (size_t)(c * 256 + wbase) * 8);
        }
        #pragma unroll
        for (int c = 0; c < 2; ++c) {
            int row = brow0 + c * 64 + rsub; row = row < rowsB ? row : rowsB - 1;
            gload16((const short*)B + (size_t)row * ldb + k0 + q * 8,
                    ldsB + (size_t)(c * 256 + wbase) * 8);
        }
        __syncthreads();
        short8v a[MI], bb[4];
        #pragma unroll
        for (int i = 0; i < MI; ++i) a[i] = A8[(wm * MI + i) * 64 + lane];
        #pragma unroll
        for (int j = 0; j < 4; ++j) bb[j] = B8[(wn * 4 + j) * 64 + lane];
        #pragma unroll
        for (int i = 0; i < MI; ++i)
            #pragma unroll
            for (int j = 0; j < 4; ++j)
                acc[i][j] = __builtin_amdgcn_mfma_f32_16x16x32_bf16(a[i], bb[j], acc[i][j], 0, 0, 0);
    }
}

#define EPI_COORDS(MI)                                      \
    const int tid  = threadIdx.x;                           \
    const int lane = tid & 63;                              \
    const int wm   = tid >> 7, wn = (tid >> 6) & 1;         \
    const int rq   = lane >> 4, cl = lane & 15; (void)rq;

// --------------------------------------------- q/k/v projection + BN (MFMA)
__global__ __launch_bounds__(256) void k_proj_m(
    const bf16* __restrict__ xt, const bf16* __restrict__ Wqkv,
    const float* __restrict__ al, const float* __restrict__ be,
    bf16* __restrict__ qbuf, bf16* __restrict__ kbuf, bf16* __restrict__ vbuf)
{
    __shared__ short ldsA[4096], ldsB[4096];
    const int n0 = blockIdx.x * 128, co0 = blockIdx.y * 128;
    const int b = blockIdx.z;
    f32x4 acc[4][4] = {};
    gemm_core<4>(xt + (size_t)b * Nn * CIN, CIN, Nn, n0,
                 Wqkv, CIN, 1536, co0, CIN, ldsA, ldsB, acc);
    EPI_COORDS(4)
    #pragma unroll
    for (int i = 0; i < 4; ++i)
        #pragma unroll
        for (int j = 0; j < 4; ++j) {
            int co = co0 + (wn * 4 + j) * 16 + cl;
            float a_ = al[co], bb_ = be[co];
            int nb = n0 + (wm * 4 + i) * 16 + rq * 4;
            #pragma unroll
            for (int r = 0; r < 4; ++r) {
                int n = nb + r;
                if (n >= Nn) continue;
                float y = a_ * acc[i][j][r] + bb_;
                if (co < 256)      qbuf[((size_t)b * Nn + n) * 256 + co]       = f2b(y);
                else if (co < 512) kbuf[((size_t)b * Nn + n) * 256 + (co-256)] = f2b(y);
                else               vbuf[((size_t)b * Nn + n) * DHn + (co-512)] = f2b(y);
            }
        }
}

// ----------------------- raw per-head logits: qk[h][n][m], K=32 (no mix/bias)
__global__ __launch_bounds__(256) void k_logits_raw(
    const bf16* __restrict__ qbuf, const bf16* __restrict__ kbuf,
    bf16* __restrict__ attn, int bi0)
{
    __shared__ short ldsA[4096], ldsB[4096];
    const int n0 = blockIdx.x * 128, m0 = blockIdx.y * 128;
    const int z = blockIdx.z, h = z & 7, bloc = z >> 3, b = bi0 + bloc;
    f32x4 acc[4][4] = {};
    gemm_core<4>(qbuf + (size_t)b * Nn * 256 + h * 32, 256, Nn, n0,
                 kbuf + (size_t)b * Nn * 256 + h * 32, 256, Nn, m0,
                 32, ldsA, ldsB, acc);
    bf16* arow = attn + (size_t)(bloc * 8 + h) * Nn * AST;
    EPI_COORDS(4)
    #pragma unroll
    for (int i = 0; i < 4; ++i)
        #pragma unroll
        for (int j = 0; j < 4; ++j) {
            int m = m0 + (wn * 4 + j) * 16 + cl;
            if (m >= Nn) continue;
            int nb = n0 + (wm * 4 + i) * 16 + rq * 4;
            #pragma unroll
            for (int r = 0; r < 4; ++r) {
                int n = nb + r;
                if (n < Nn) arow[(size_t)n * AST + m] = f2b(acc[i][j][r]);
            }
        }
}

// --- fused: th1 mix (+abfull bias) + softmax + th2 mix, REGISTER-resident
// thread t owns m-chunk [4t, 4t+4) for t<196; all 8 heads in registers.
__global__ __launch_bounds__(256) void k_softmax_mix(
    bf16* __restrict__ attn_all, const bf16* __restrict__ abfull,
    const bf16* __restrict__ W1, const bf16* __restrict__ W2, const bf16* __restrict__ b2v)
{
    const int n = blockIdx.x, bloc = blockIdx.y;
    const int tid = threadIdx.x;
    bf16* base = attn_all + (size_t)bloc * 8 * Nn * AST;
    __shared__ float w1s[64], w2s[64], b2sh[8], mxs[8], lis[8], wred[4][8];
    if (tid < 64) { w1s[tid] = b2f(W1[tid]) * 0.17677669529663687f; w2s[tid] = b2f(W2[tid]); }
    if (tid < 8)  b2sh[tid] = b2f(b2v[tid]);
    __syncthreads();

    const bool live = tid < 196;
    const int m0 = (live ? tid : 195) * 4;

    // load raw S: 8 heads x 4 m (short4 vector loads, coalesced)
    float raw[8][4];
    #pragma unroll
    for (int h = 0; h < 8; ++h) {
        short4v v = *(const short4v*)(base + ((size_t)h * Nn + n) * AST + m0);
        #pragma unroll
        for (int u = 0; u < 4; ++u) raw[h][u] = su2f(v[u]);
    }

    // th1 mix + bias, per-g block max
    float out[8][4];
    #pragma unroll
    for (int g = 0; g < 8; ++g) {
        short4v bv = *(const short4v*)(abfull + ((size_t)g * Nn + n) * AST + m0);
        #pragma unroll
        for (int u = 0; u < 4; ++u) {
            float a = su2f(bv[u]);
            #pragma unroll
            for (int h = 0; h < 8; ++h) a += w1s[g * 8 + h] * raw[h][u];
            out[g][u] = a;
        }
        float m = live ? fmaxf(fmaxf(out[g][0], out[g][1]), fmaxf(out[g][2], out[g][3]))
                       : -1e30f;
        #pragma unroll
        for (int s = 32; s > 0; s >>= 1) m = fmaxf(m, __shfl_xor(m, s, 64));
        if ((tid & 63) == 0) wred[tid >> 6][g] = m;
    }
    __syncthreads();
    if (tid < 8)
        mxs[tid] = fmaxf(fmaxf(wred[0][tid], wred[1][tid]), fmaxf(wred[2][tid], wred[3][tid]));
    __syncthreads();

    // exp + block sum
    #pragma unroll
    for (int g = 0; g < 8; ++g) {
        float mg = mxs[g];
        float s = 0.f;
        #pragma unroll
        for (int u = 0; u < 4; ++u) {
            float ev = live ? __expf(out[g][u] - mg) : 0.f;
            out[g][u] = ev;
            s += ev;
        }
        #pragma unroll
        for (int sh = 32; sh > 0; sh >>= 1) s += __shfl_xor(s, sh, 64);
        if ((tid & 63) == 0) wred[tid >> 6][g] = s;
    }
    __syncthreads();
    if (tid < 8)
        lis[tid] = 1.f / (wred[0][tid] + wred[1][tid] + wred[2][tid] + wred[3][tid]);
    __syncthreads();

    // normalize + th2 mix + store (P2 pads left as-is: PV multiplies them by vt zeros)
    #pragma unroll
    for (int h = 0; h < 8; ++h) {
        float lh = lis[h];
        #pragma unroll
        for (int u = 0; u < 4; ++u) out[h][u] *= lh;
    }
    if (live) {
        #pragma unroll
        for (int g = 0; g < 8; ++g) {
            short4v sv;
            #pragma unroll
            for (int u = 0; u < 4; ++u) {
                float a = b2sh[g];
                #pragma unroll
                for (int h = 0; h < 8; ++h) a += w2s[g * 8 + h] * out[h][u];
                bf16 bb = f2b(a);
                sv[u] = *reinterpret_cast<short*>(&bb);
            }
            *(short4v*)(base + ((size_t)g * Nn + n) * AST + m0) = sv;
        }
    }
}

// ------------------------------------------------ PV: obuf[b][n][c] = P2 · v
__global__ __launch_bounds__(256) void k_pv_m(
    const bf16* __restrict__ attn, const bf16* __restrict__ vt,
    bf16* __restrict__ obuf, int bi0)
{
    __shared__ short ldsA[2048], ldsB[4096];
    const int n0 = blockIdx.x * 64;
    const int z = blockIdx.z, g = z & 7, bloc = z >> 3, b = bi0 + bloc;
    f32x4 acc[2][4] = {};
    gemm_core<2>(attn + (size_t)(bloc * 8 + g) * Nn * AST, AST, Nn, n0,
                 vt + ((size_t)b * DHn + g * 128) * AST, AST, 128, 0,
                 AST, ldsA, ldsB, acc);
    bf16* ob = obuf + (size_t)b * Nn * DHn + g * 128;
    EPI_COORDS(2)
    #pragma unroll
    for (int i = 0; i < 2; ++i)
        #pragma unroll
        for (int j = 0; j < 4; ++j) {
            int d = (wn * 4 + j) * 16 + cl;
            int nb = n0 + (wm * 2 + i) * 16 + rq * 4;
            #pragma unroll
            for (int r = 0; r < 4; ++r) {
                int n = nb + r;
                if (n < Nn) ob[(size_t)n * DHn + d] = f2b(acc[i][j][r]);
            }
        }
}

// ------------------- depthwise conv+BN, ADDS into obuf (o += vl), vectorized
__global__ __launch_bounds__(256) void k_dwconv_add(
    const bf16* __restrict__ vbuf, const bf16* __restrict__ Wvl,
    const bf16* __restrict__ bvl, const bf16* __restrict__ vls, const bf16* __restrict__ vlb,
    bf16* __restrict__ obuf)
{
    const int t = threadIdx.x;
    const int n = blockIdx.y * 2 + (t >> 7);
    const int bi = blockIdx.z;
    const int c0 = (t & 127) * 8;
    const int h = n / RESn, w = n % RESn;
    float acc[8] = {};
    #pragma unroll
    for (int dh = -1; dh <= 1; ++dh)
        #pragma unroll
        for (int dw = -1; dw <= 1; ++dw) {
            int hh = h + dh, ww = w + dw;
            if (hh < 0 || hh >= RESn || ww < 0 || ww >= RESn) continue;
            short8v v = *(const short8v*)&vbuf[((size_t)bi * Nn + hh * RESn + ww) * DHn + c0];
            int widx = (dh + 1) * 3 + (dw + 1);
            #pragma unroll
            for (int u = 0; u < 8; ++u)
                acc[u] += b2f(Wvl[(size_t)(c0 + u) * 9 + widx]) * su2f(v[u]);
        }
    size_t off = ((size_t)bi * Nn + n) * DHn + c0;
    short8v ov = *(short8v*)&obuf[off];
    short8v res;
    #pragma unroll
    for (int u = 0; u < 8; ++u) {
        float s = b2f(vls[c0 + u]);
        float vl = s * (acc[u] + b2f(bvl[c0 + u])) + b2f(vlb[c0 + u]);
        bf16 bo = f2b(su2f(ov[u]) + vl);
        res[u] = *reinterpret_cast<short*>(&bo);
    }
    *(short8v*)&obuf[off] = res;
}

// --------------------------------------------- output projection + BN (MFMA)
__global__ __launch_bounds__(256) void k_outproj_m(
    const bf16* __restrict__ Wp, const bf16* __restrict__ obuf,
    const bf16* __restrict__ bp, const bf16* __restrict__ ps, const bf16* __restrict__ pb,
    void* __restrict__ outv, const int* __restrict__ flag)
{
    __shared__ short ldsA[2048], ldsB[4096];
    const int n0 = blockIdx.x * 128, oc0 = blockIdx.y * 64;
    const int b = blockIdx.z;
    f32x4 acc[2][4] = {};
    gemm_core<2>(Wp, DHn, 384, oc0,
                 obuf + (size_t)b * Nn * DHn, DHn, Nn, n0,
                 DHn, ldsA, ldsB, acc);
    const int isb = *flag;
    EPI_COORDS(2)
    #pragma unroll
    for (int i = 0; i < 2; ++i)
        #pragma unroll
        for (int j = 0; j < 4; ++j) {
            int n = n0 + (wn * 4 + j) * 16 + cl;
            if (n >= Nn) continue;
            int ocb = oc0 + (wm * 2 + i) * 16 + rq * 4;
            #pragma unroll
            for (int r = 0; r < 4; ++r) {
                int oc = ocb + r;
                float a_ = b2f(ps[oc]);
                float be_ = b2f(bp[oc]) * a_ + b2f(pb[oc]);
                float y = a_ * acc[i][j][r] + be_;
                size_t idx = ((size_t)b * CIN + oc) * Nn + n;
                if (isb) ((bf16*)outv)[idx] = f2b(y);
                else     ((float*)outv)[idx] = y;
            }
        }
}

extern "C" void kernel_launch(void* const* d_in, const int* in_sizes, int n_in,
                              void* d_out, int out_size, void* d_ws, size_t ws_size,
                              hipStream_t stream)
{
    char* ws = (char*)d_ws;
    auto align256 = [](size_t v) { return (v + 255) & ~(size_t)255; };

    size_t off = 0;
    size_t off_flag = off;            off = align256(off + 4);
    size_t p_off[26];
    for (int i = 0; i < 26; ++i) { p_off[i] = off; off = align256(off + (size_t)in_sizes[i] * 2); }
    size_t off_mb   = off; off = align256(off + (size_t)8 * Nn * 4);
    size_t off_ab   = off; off = align256(off + (size_t)8 * Nn * AST * 2);
    size_t off_q    = off; off = align256(off + (size_t)Bn * Nn * 256 * 2);
    size_t off_k    = off; off = align256(off + (size_t)Bn * Nn * 256 * 2);
    size_t off_v    = off; off = align256(off + (size_t)Bn * Nn * DHn * 2);
    size_t off_vt   = off; off = align256(off + (size_t)Bn * DHn * AST * 2);
    size_t off_o    = off; off = align256(off + (size_t)Bn * Nn * DHn * 2);
    size_t off_xt   = off; off = align256(off + (size_t)Bn * Nn * CIN * 2);
    size_t off_wqkv = off; off = align256(off + (size_t)1536 * CIN * 2);
    size_t off_al   = off; off = align256(off + (size_t)1536 * 4);
    size_t off_be   = off; off = align256(off + (size_t)1536 * 4);
    size_t base = off;

    const size_t attn_per_b = (size_t)8 * Nn * AST * 2;
    int GB = 0;
    const int cand[4] = {8, 4, 2, 1};
    for (int ci = 0; ci < 4; ++ci) {
        if (base + (size_t)cand[ci] * attn_per_b + 512 <= ws_size) { GB = cand[ci]; break; }
    }
    if (!GB) return; // ws too small -> zeros out (diagnostic absmax ~17.4)

    size_t off_attn = base;

    int*  flag = (int*)(ws + off_flag);
    bf16* Pb[26];
    for (int i = 0; i < 26; ++i) Pb[i] = (bf16*)(ws + p_off[i]);
    float* mb    = (float*)(ws + off_mb);
    bf16* abfull = (bf16*)(ws + off_ab);
    bf16* qbuf  = (bf16*)(ws + off_q);
    bf16* kbuf  = (bf16*)(ws + off_k);
    bf16* vbuf  = (bf16*)(ws + off_v);
    bf16* vt    = (bf16*)(ws + off_vt);
    bf16* obuf  = (bf16*)(ws + off_o);
    bf16* xt    = (bf16*)(ws + off_xt);
    bf16* wqkv  = (bf16*)(ws + off_wqkv);
    float* alf  = (float*)(ws + off_al);
    float* bef  = (float*)(ws + off_be);
    bf16* attn  = (bf16*)(ws + off_attn);
    const int* idxs = (const int*)d_in[26];

    k_detect<<<1, 64, 0, stream>>>((const unsigned*)d_in[0], flag);

    ConvArgs ca;
    for (int i = 0; i < 26; ++i) { ca.src[i] = d_in[i]; ca.dstoff[i] = p_off[i]; ca.n[i] = in_sizes[i]; }
    k_convb_all<<<dim3(256, 26), 256, 0, stream>>>(ca, ws, flag);

    bf16 *x = Pb[0], *Wq = Pb[1], *bq = Pb[2], *qs = Pb[3], *qb = Pb[4],
         *Wk = Pb[5], *bk = Pb[6], *ks = Pb[7], *kb = Pb[8],
         *Wv = Pb[9], *bv = Pb[10], *vs = Pb[11], *vb = Pb[12],
         *Wvl = Pb[13], *bvl = Pb[14], *vls = Pb[15], *vlb = Pb[16],
         *W1 = Pb[17], *b1 = Pb[18], *W2 = Pb[19], *b2v = Pb[20],
         *Wp = Pb[21], *bp = Pb[22], *ps = Pb[23], *pb = Pb[24], *ab = Pb[25];

    k_wpack<<<dim3((1536 * 48 + 255) / 256), 256, 0, stream>>>(Wq, Wk, Wv, wqkv);
    k_affine<<<dim3(6), 256, 0, stream>>>(bq, qs, qb, bk, ks, kb, bv, vs, vb, alf, bef);
    k_mixbias<<<dim3((8 * Nn + 255) / 256), 256, 0, stream>>>(ab, W1, b1, mb);
    k_abfull<<<dim3(392), 256, 0, stream>>>(mb, idxs, abfull);
    k_xt<<<dim3(25, 12, 8), 256, 0, stream>>>(x, xt);

    k_proj_m<<<dim3(7, 12, 8), 256, 0, stream>>>(xt, wqkv, alf, bef, qbuf, kbuf, vbuf);
    k_vt<<<dim3(25, 32, 8), 256, 0, stream>>>(vbuf, vt);

    for (int bi0 = 0; bi0 < Bn; bi0 += GB) {
        k_logits_raw<<<dim3(7, 7, GB * 8), 256, 0, stream>>>(qbuf, kbuf, attn, bi0);
        k_softmax_mix<<<dim3(Nn, GB), 256, 0, stream>>>(attn, abfull, W1, W2, b2v);
        k_pv_m<<<dim3(13, 1, GB * 8), 256, 0, stream>>>(attn, vt, obuf, bi0);
    }

    k_dwconv_add<<<dim3(1, Nn / 2, 8), 256, 0, stream>>>(vbuf, Wvl, bvl, vls, vlb, obuf);
    k_outproj_m<<<dim3(7, 6, 8), 256, 0, stream>>>(Wp, obuf, bp, ps, pb, d_out, flag);
}

// Round 8
// 276.115 us; speedup vs baseline: 1.2991x; 1.0671x over previous
//
#include <hip/hip_runtime.h>
#include <hip/hip_bf16.h>

typedef __hip_bfloat16 bf16;
typedef __attribute__((ext_vector_type(8))) short short8v;
typedef __attribute__((ext_vector_type(4))) short short4v;
typedef __attribute__((ext_vector_type(4))) float f32x4;
typedef __attribute__((ext_vector_type(2))) float f32x2;

__device__ __forceinline__ float b2f(bf16 v){ return __bfloat162float(v); }
__device__ __forceinline__ bf16  f2b(float v){ return __float2bfloat16(v); }
__device__ __forceinline__ float su2f(short s){
    unsigned short us = (unsigned short)s;
    return __bfloat162float(*reinterpret_cast<bf16*>(&us));
}
__device__ __forceinline__ float ldf(const void* t, size_t i, int isb){
    return isb ? b2f(((const bf16*)t)[i]) : ((const float*)t)[i];
}

constexpr int Bn = 8, CIN = 384, RESn = 28, Nn = 784, DHn = 1024;
constexpr int AST = 800;   // padded attn/vt K-stride (25*32)

// ---------------------------------------------------- async global->LDS 16B
__device__ __forceinline__ void gload16(const void* g, void* l)
{
    __builtin_amdgcn_global_load_lds(
        (const __attribute__((address_space(1))) void*)g,
        (__attribute__((address_space(3))) void*)l, 16, 0, 0);
}

// -------------------------------------------------- dtype detector (1 thread)
__global__ void k_detect(const unsigned* __restrict__ xw, int* __restrict__ flag)
{
    if (blockIdx.x == 0 && threadIdx.x == 0) {
        int cnt = 0;
        for (int i = 0; i < 256; ++i) {
            unsigned lo = xw[i] & 0xFFFFu;
            int e = (int)((lo >> 7) & 0xFF);
            if (e >= 112 && e <= 132) ++cnt;
        }
        *flag = (cnt >= 128) ? 1 : 0;
    }
}

// ---------------- fused prep: wpack | affine | mixbias (reads d_in raw + flag)
struct PtrArgs { const void* p[26]; };
__global__ __launch_bounds__(256) void k_prep(PtrArgs a, bf16* __restrict__ Wqkv,
                                              float* __restrict__ al, float* __restrict__ be,
                                              float* __restrict__ mb, const int* __restrict__ flag)
{
    const int isb = *flag;
    const int tid = threadIdx.x;
    const int role = blockIdx.y;
    if (role == 0) {
        int stride = gridDim.x * 256;
        for (int e = blockIdx.x * 256 + tid; e < 1536 * 384; e += stride) {
            int co = e / 384, k = e % 384;
            const void* src; int lc;
            if (co < 256)      { src = a.p[1]; lc = co; }
            else if (co < 512) { src = a.p[5]; lc = co - 256; }
            else               { src = a.p[9]; lc = co - 512; }
            Wqkv[e] = f2b(ldf(src, (size_t)lc * 384 + k, isb));
        }
    } else if (role == 1) {
        int co = blockIdx.x * 256 + tid;
        if (co < 1536) {
            const void *b_, *s_, *h_; int lc;
            if (co < 256)      { b_ = a.p[2];  s_ = a.p[3];  h_ = a.p[4];  lc = co; }
            else if (co < 512) { b_ = a.p[6];  s_ = a.p[7];  h_ = a.p[8];  lc = co - 256; }
            else               { b_ = a.p[10]; s_ = a.p[11]; h_ = a.p[12]; lc = co - 512; }
            float aa = ldf(s_, lc, isb);
            al[co] = aa;
            be[co] = ldf(b_, lc, isb) * aa + ldf(h_, lc, isb);
        }
    } else {
        int i = blockIdx.x * 256 + tid;
        if (i < 8 * Nn) {
            int g = i / Nn, p = i % Nn;
            float acc = ldf(a.p[18], g, isb);
            #pragma unroll
            for (int h = 0; h < 8; ++h)
                acc += ldf(a.p[17], g * 8 + h, isb) * ldf(a.p[25], (size_t)h * Nn + p, isb);
            mb[i] = acc;
        }
    }
}

// ------------------------------------- convert needed tensors -> bf16
struct ConvArgs { const void* src[11]; unsigned long long dstoff[11]; int n[11]; };
__global__ void k_convb_all(ConvArgs a, char* __restrict__ ws, const int* __restrict__ flag)
{
    int i = blockIdx.y;
    int n = a.n[i];
    const void* s = a.src[i];
    bf16* d = (bf16*)(ws + a.dstoff[i]);
    int isb = *flag;
    int stride = gridDim.x * blockDim.x;
    for (int t = blockIdx.x * blockDim.x + threadIdx.x; t < n; t += stride)
        d[t] = isb ? ((const bf16*)s)[t] : f2b(((const float*)s)[t]);
}

// ------------------- expand mb through idx: abfull[g][n][m] (b-independent)
__global__ __launch_bounds__(256) void k_abfull(
    const float* __restrict__ mb, const int* __restrict__ idxs,
    bf16* __restrict__ abfull)
{
    __shared__ float mbs[8][Nn];
    const int tid = threadIdx.x;
    for (int i = tid; i < 8 * Nn; i += 256) ((float*)mbs)[i] = mb[i];
    __syncthreads();
    const int nstart = blockIdx.x * 2;
    for (int n = nstart; n < nstart + 2; ++n) {
        for (int m = tid; m < Nn; m += 256) {
            int id = idxs[(size_t)n * Nn + m];
            #pragma unroll
            for (int g = 0; g < 8; ++g)
                abfull[((size_t)g * Nn + n) * AST + m] = f2b(mbs[g][id]);
        }
    }
}

// ------------- x transpose + inline convert: [b][384][784] -> [b][784][384]
__global__ __launch_bounds__(256) void k_xt(const void* __restrict__ xr, bf16* __restrict__ xt,
                                            const int* __restrict__ flag)
{
    const int isb = *flag;
    __shared__ bf16 t[32][33];
    int b = blockIdx.z, n0 = blockIdx.x * 32, c0 = blockIdx.y * 32;
    int tid = threadIdx.x;
    for (int i = tid; i < 1024; i += 256) {
        int r = i >> 5, c = i & 31;
        int n = n0 + c;
        t[r][c] = (n < Nn) ? f2b(ldf(xr, ((size_t)b * CIN + c0 + r) * Nn + n, isb)) : f2b(0.f);
    }
    __syncthreads();
    for (int i = tid; i < 1024; i += 256) {
        int r = i >> 5, c = i & 31;
        int n = n0 + r;
        if (n < Nn) xt[((size_t)b * Nn + n) * CIN + c0 + c] = t[c][r];
    }
}

// --------------------- v transpose: [n][c] -> [c][n] (stride AST, zero-padded)
__global__ __launch_bounds__(256) void k_vt(const bf16* __restrict__ vbuf, bf16* __restrict__ vt)
{
    __shared__ bf16 t[32][33];
    int b = blockIdx.z, n0 = blockIdx.x * 32, c0 = blockIdx.y * 32;
    int tid = threadIdx.x;
    for (int i = tid; i < 1024; i += 256) {
        int r = i >> 5, c = i & 31;
        int n = n0 + r;
        t[r][c] = (n < Nn) ? vbuf[((size_t)b * Nn + n) * DHn + c0 + c] : f2b(0.f);
    }
    __syncthreads();
    for (int i = tid; i < 1024; i += 256) {
        int r = i >> 5, c = i & 31;
        int n = n0 + c;   // n < 800 always (25*32 grid)
        vt[((size_t)b * DHn + c0 + r) * AST + n] = t[c][r];
    }
}

// ------------------- generic MFMA core: tile (MI*32) x 128, BK=32, gload_lds
template<int MI>
__device__ __forceinline__ void gemm_core(
    const bf16* __restrict__ A, int lda, int rowsA, int arow0,
    const bf16* __restrict__ B, int ldb, int rowsB, int brow0,
    int K, short* ldsA, short* ldsB, f32x4 (&acc)[MI][4])
{
    const int tid  = threadIdx.x;
    const int lane = tid & 63;
    const int wm   = tid >> 7, wn = (tid >> 6) & 1;
    const int rsub = ((tid >> 6) << 4) | (tid & 15);
    const int q    = (tid >> 4) & 3;
    const int wbase = tid & 192;
    const short8v* A8 = (const short8v*)ldsA;
    const short8v* B8 = (const short8v*)ldsB;

    for (int k0 = 0; k0 < K; k0 += 32) {
        __syncthreads();
        #pragma unroll
        for (int c = 0; c < MI / 2; ++c) {
            int row = arow0 + c * 64 + rsub; row = row < rowsA ? row : rowsA - 1;
            gload16((const short*)A + (size_t)row * lda + k0 + q * 8,
                    ldsA + (size_t)(c * 256 + wbase) * 8);
        }
        #pragma unroll
        for (int c = 0; c < 2; ++c) {
            int row = brow0 + c * 64 + rsub; row = row < rowsB ? row : rowsB - 1;
            gload16((const short*)B + (size_t)row * ldb + k0 + q * 8,
                    ldsB + (size_t)(c * 256 + wbase) * 8);
        }
        __syncthreads();
        short8v a[MI], bb[4];
        #pragma unroll
        for (int i = 0; i < MI; ++i) a[i] = A8[(wm * MI + i) * 64 + lane];
        #pragma unroll
        for (int j = 0; j < 4; ++j) bb[j] = B8[(wn * 4 + j) * 64 + lane];
        #pragma unroll
        for (int i = 0; i < MI; ++i)
            #pragma unroll
            for (int j = 0; j < 4; ++j)
                acc[i][j] = __builtin_amdgcn_mfma_f32_16x16x32_bf16(a[i], bb[j], acc[i][j], 0, 0, 0);
    }
}

#define EPI_COORDS(MI)                                      \
    const int tid  = threadIdx.x;                           \
    const int lane = tid & 63;                              \
    const int wm   = tid >> 7, wn = (tid >> 6) & 1;         \
    const int rq   = lane >> 4, cl = lane & 15; (void)rq;

// --------------------------------------------- q/k/v projection + BN (MFMA)
__global__ __launch_bounds__(256) void k_proj_m(
    const bf16* __restrict__ xt, const bf16* __restrict__ Wqkv,
    const float* __restrict__ al, const float* __restrict__ be,
    bf16* __restrict__ qbuf, bf16* __restrict__ kbuf, bf16* __restrict__ vbuf)
{
    __shared__ short ldsA[4096], ldsB[4096];
    const int n0 = blockIdx.x * 128, co0 = blockIdx.y * 128;
    const int b = blockIdx.z;
    f32x4 acc[4][4] = {};
    gemm_core<4>(xt + (size_t)b * Nn * CIN, CIN, Nn, n0,
                 Wqkv, CIN, 1536, co0, CIN, ldsA, ldsB, acc);
    EPI_COORDS(4)
    #pragma unroll
    for (int i = 0; i < 4; ++i)
        #pragma unroll
        for (int j = 0; j < 4; ++j) {
            int co = co0 + (wn * 4 + j) * 16 + cl;
            float a_ = al[co], bb_ = be[co];
            int nb = n0 + (wm * 4 + i) * 16 + rq * 4;
            #pragma unroll
            for (int r = 0; r < 4; ++r) {
                int n = nb + r;
                if (n >= Nn) continue;
                float y = a_ * acc[i][j][r] + bb_;
                if (co < 256)      qbuf[((size_t)b * Nn + n) * 256 + co]       = f2b(y);
                else if (co < 512) kbuf[((size_t)b * Nn + n) * 256 + (co-256)] = f2b(y);
                else               vbuf[((size_t)b * Nn + n) * DHn + (co-512)] = f2b(y);
            }
        }
}

// ----------------------- raw per-head logits: qk[h][n][m], K=32 (no mix/bias)
__global__ __launch_bounds__(256) void k_logits_raw(
    const bf16* __restrict__ qbuf, const bf16* __restrict__ kbuf,
    bf16* __restrict__ attn, int bi0)
{
    __shared__ short ldsA[4096], ldsB[4096];
    const int n0 = blockIdx.x * 128, m0 = blockIdx.y * 128;
    const int z = blockIdx.z, h = z & 7, bloc = z >> 3, b = bi0 + bloc;
    f32x4 acc[4][4] = {};
    gemm_core<4>(qbuf + (size_t)b * Nn * 256 + h * 32, 256, Nn, n0,
                 kbuf + (size_t)b * Nn * 256 + h * 32, 256, Nn, m0,
                 32, ldsA, ldsB, acc);
    bf16* arow = attn + (size_t)(bloc * 8 + h) * Nn * AST;
    EPI_COORDS(4)
    #pragma unroll
    for (int i = 0; i < 4; ++i)
        #pragma unroll
        for (int j = 0; j < 4; ++j) {
            int m = m0 + (wn * 4 + j) * 16 + cl;
            if (m >= Nn) continue;
            int nb = n0 + (wm * 4 + i) * 16 + rq * 4;
            #pragma unroll
            for (int r = 0; r < 4; ++r) {
                int n = nb + r;
                if (n < Nn) arow[(size_t)n * AST + m] = f2b(acc[i][j][r]);
            }
        }
}

// --- fused: th1 mix (+abfull) + softmax (no-max, clamp) + th2 mix, registers
__global__ __launch_bounds__(256) void k_softmax_mix(
    bf16* __restrict__ attn_all, const bf16* __restrict__ abfull,
    const bf16* __restrict__ W1, const bf16* __restrict__ W2, const bf16* __restrict__ b2v)
{
    const int n = blockIdx.x, bloc = blockIdx.y;
    const int tid = threadIdx.x;
    bf16* base = attn_all + (size_t)bloc * 8 * Nn * AST;
    __shared__ float w1s[64], w2s[64], b2sh[8], lis[8], wred[4][8];
    if (tid < 64) { w1s[tid] = b2f(W1[tid]) * 0.17677669529663687f; w2s[tid] = b2f(W2[tid]); }
    if (tid < 8)  b2sh[tid] = b2f(b2v[tid]);
    __syncthreads();

    const bool live = tid < 196;
    const int m0 = (live ? tid : 195) * 4;

    // load raw S: 8 heads x 4 m, packed as f32x2 pairs
    f32x2 raw2[8][2];
    #pragma unroll
    for (int h = 0; h < 8; ++h) {
        short4v v = *(const short4v*)(base + ((size_t)h * Nn + n) * AST + m0);
        raw2[h][0] = f32x2{su2f(v[0]), su2f(v[1])};
        raw2[h][1] = f32x2{su2f(v[2]), su2f(v[3])};
    }

    // th1 mix + bias + exp (no max subtraction; clamp for overflow safety)
    float out[8][4];
    #pragma unroll
    for (int g = 0; g < 8; ++g) {
        short4v bv = *(const short4v*)(abfull + ((size_t)g * Nn + n) * AST + m0);
        f32x2 a0 = {su2f(bv[0]), su2f(bv[1])};
        f32x2 a1 = {su2f(bv[2]), su2f(bv[3])};
        #pragma unroll
        for (int h = 0; h < 8; ++h) {
            float w = w1s[g * 8 + h];
            f32x2 wv = {w, w};
            a0 += raw2[h][0] * wv;
            a1 += raw2[h][1] * wv;
        }
        out[g][0] = __expf(fminf(a0[0], 60.f));
        out[g][1] = __expf(fminf(a0[1], 60.f));
        out[g][2] = __expf(fminf(a1[0], 60.f));
        out[g][3] = __expf(fminf(a1[1], 60.f));
        float s = live ? (out[g][0] + out[g][1]) + (out[g][2] + out[g][3]) : 0.f;
        #pragma unroll
        for (int sh = 32; sh > 0; sh >>= 1) s += __shfl_xor(s, sh, 64);
        if ((tid & 63) == 0) wred[tid >> 6][g] = s;
    }
    __syncthreads();
    if (tid < 8)
        lis[tid] = 1.f / (wred[0][tid] + wred[1][tid] + wred[2][tid] + wred[3][tid]);
    __syncthreads();

    // normalized P packed; th2 mix packed; store
    f32x2 p2[8][2];
    #pragma unroll
    for (int h = 0; h < 8; ++h) {
        float lh = lis[h];
        p2[h][0] = f32x2{out[h][0] * lh, out[h][1] * lh};
        p2[h][1] = f32x2{out[h][2] * lh, out[h][3] * lh};
    }
    if (live) {
        #pragma unroll
        for (int g = 0; g < 8; ++g) {
            f32x2 acc0 = {b2sh[g], b2sh[g]};
            f32x2 acc1 = acc0;
            #pragma unroll
            for (int h = 0; h < 8; ++h) {
                float w = w2s[g * 8 + h];
                f32x2 wv = {w, w};
                acc0 += p2[h][0] * wv;
                acc1 += p2[h][1] * wv;
            }
            short4v sv;
            bf16 b0 = f2b(acc0[0]); sv[0] = *reinterpret_cast<short*>(&b0);
            bf16 b1 = f2b(acc0[1]); sv[1] = *reinterpret_cast<short*>(&b1);
            bf16 b2 = f2b(acc1[0]); sv[2] = *reinterpret_cast<short*>(&b2);
            bf16 b3 = f2b(acc1[1]); sv[3] = *reinterpret_cast<short*>(&b3);
            *(short4v*)(base + ((size_t)g * Nn + n) * AST + m0) = sv;
        }
    }
}

// ------------------------------------------------ PV: obuf[b][n][c] = P2 · v
__global__ __launch_bounds__(256) void k_pv_m(
    const bf16* __restrict__ attn, const bf16* __restrict__ vt,
    bf16* __restrict__ obuf, int bi0)
{
    __shared__ short ldsA[2048], ldsB[4096];
    const int n0 = blockIdx.x * 64;
    const int z = blockIdx.z, g = z & 7, bloc = z >> 3, b = bi0 + bloc;
    f32x4 acc[2][4] = {};
    gemm_core<2>(attn + (size_t)(bloc * 8 + g) * Nn * AST, AST, Nn, n0,
                 vt + ((size_t)b * DHn + g * 128) * AST, AST, 128, 0,
                 AST, ldsA, ldsB, acc);
    bf16* ob = obuf + (size_t)b * Nn * DHn + g * 128;
    EPI_COORDS(2)
    #pragma unroll
    for (int i = 0; i < 2; ++i)
        #pragma unroll
        for (int j = 0; j < 4; ++j) {
            int d = (wn * 4 + j) * 16 + cl;
            int nb = n0 + (wm * 2 + i) * 16 + rq * 4;
            #pragma unroll
            for (int r = 0; r < 4; ++r) {
                int n = nb + r;
                if (n < Nn) ob[(size_t)n * DHn + d] = f2b(acc[i][j][r]);
            }
        }
}

// ------------------- depthwise conv+BN, ADDS into obuf (o += vl), vectorized
__global__ __launch_bounds__(256) void k_dwconv_add(
    const bf16* __restrict__ vbuf, const bf16* __restrict__ Wvl,
    const bf16* __restrict__ bvl, const bf16* __restrict__ vls, const bf16* __restrict__ vlb,
    bf16* __restrict__ obuf)
{
    const int t = threadIdx.x;
    const int n = blockIdx.y * 2 + (t >> 7);
    const int bi = blockIdx.z;
    const int c0 = (t & 127) * 8;
    const int h = n / RESn, w = n % RESn;
    float acc[8] = {};
    #pragma unroll
    for (int dh = -1; dh <= 1; ++dh)
        #pragma unroll
        for (int dw = -1; dw <= 1; ++dw) {
            int hh = h + dh, ww = w + dw;
            if (hh < 0 || hh >= RESn || ww < 0 || ww >= RESn) continue;
            short8v v = *(const short8v*)&vbuf[((size_t)bi * Nn + hh * RESn + ww) * DHn + c0];
            int widx = (dh + 1) * 3 + (dw + 1);
            #pragma unroll
            for (int u = 0; u < 8; ++u)
                acc[u] += b2f(Wvl[(size_t)(c0 + u) * 9 + widx]) * su2f(v[u]);
        }
    size_t off = ((size_t)bi * Nn + n) * DHn + c0;
    short8v ov = *(short8v*)&obuf[off];
    short8v res;
    #pragma unroll
    for (int u = 0; u < 8; ++u) {
        float s = b2f(vls[c0 + u]);
        float vl = s * (acc[u] + b2f(bvl[c0 + u])) + b2f(vlb[c0 + u]);
        bf16 bo = f2b(su2f(ov[u]) + vl);
        res[u] = *reinterpret_cast<short*>(&bo);
    }
    *(short8v*)&obuf[off] = res;
}

// --------------------------------------------- output projection + BN (MFMA)
__global__ __launch_bounds__(256) void k_outproj_m(
    const bf16* __restrict__ Wp, const bf16* __restrict__ obuf,
    const bf16* __restrict__ bp, const bf16* __restrict__ ps, const bf16* __restrict__ pb,
    void* __restrict__ outv, const int* __restrict__ flag)
{
    __shared__ short ldsA[2048], ldsB[4096];
    const int n0 = blockIdx.x * 128, oc0 = blockIdx.y * 64;
    const int b = blockIdx.z;
    f32x4 acc[2][4] = {};
    gemm_core<2>(Wp, DHn, 384, oc0,
                 obuf + (size_t)b * Nn * DHn, DHn, Nn, n0,
                 DHn, ldsA, ldsB, acc);
    const int isb = *flag;
    EPI_COORDS(2)
    #pragma unroll
    for (int i = 0; i < 2; ++i)
        #pragma unroll
        for (int j = 0; j < 4; ++j) {
            int n = n0 + (wn * 4 + j) * 16 + cl;
            if (n >= Nn) continue;
            int ocb = oc0 + (wm * 2 + i) * 16 + rq * 4;
            #pragma unroll
            for (int r = 0; r < 4; ++r) {
                int oc = ocb + r;
                float a_ = b2f(ps[oc]);
                float be_ = b2f(bp[oc]) * a_ + b2f(pb[oc]);
                float y = a_ * acc[i][j][r] + be_;
                size_t idx = ((size_t)b * CIN + oc) * Nn + n;
                if (isb) ((bf16*)outv)[idx] = f2b(y);
                else     ((float*)outv)[idx] = y;
            }
        }
}

extern "C" void kernel_launch(void* const* d_in, const int* in_sizes, int n_in,
                              void* d_out, int out_size, void* d_ws, size_t ws_size,
                              hipStream_t stream)
{
    char* ws = (char*)d_ws;
    auto align256 = [](size_t v) { return (v + 255) & ~(size_t)255; };

    size_t off = 0;
    size_t off_flag = off;            off = align256(off + 4);
    size_t p_off[26];
    for (int i = 0; i < 26; ++i) { p_off[i] = off; off = align256(off + (size_t)in_sizes[i] * 2); }
    size_t off_mb   = off; off = align256(off + (size_t)8 * Nn * 4);
    size_t off_ab   = off; off = align256(off + (size_t)8 * Nn * AST * 2);
    size_t off_q    = off; off = align256(off + (size_t)Bn * Nn * 256 * 2);
    size_t off_k    = off; off = align256(off + (size_t)Bn * Nn * 256 * 2);
    size_t off_v    = off; off = align256(off + (size_t)Bn * Nn * DHn * 2);
    size_t off_vt   = off; off = align256(off + (size_t)Bn * DHn * AST * 2);
    size_t off_o    = off; off = align256(off + (size_t)Bn * Nn * DHn * 2);
    size_t off_xt   = off; off = align256(off + (size_t)Bn * Nn * CIN * 2);
    size_t off_wqkv = off; off = align256(off + (size_t)1536 * CIN * 2);
    size_t off_al   = off; off = align256(off + (size_t)1536 * 4);
    size_t off_be   = off; off = align256(off + (size_t)1536 * 4);
    size_t base = off;

    const size_t attn_per_b = (size_t)8 * Nn * AST * 2;
    int GB = 0;
    const int cand[4] = {8, 4, 2, 1};
    for (int ci = 0; ci < 4; ++ci) {
        if (base + (size_t)cand[ci] * attn_per_b + 512 <= ws_size) { GB = cand[ci]; break; }
    }
    if (!GB) return; // ws too small -> zeros out (diagnostic absmax ~17.4)

    size_t off_attn = base;

    int*  flag = (int*)(ws + off_flag);
    bf16* Pb[26];
    for (int i = 0; i < 26; ++i) Pb[i] = (bf16*)(ws + p_off[i]);
    float* mb    = (float*)(ws + off_mb);
    bf16* abfull = (bf16*)(ws + off_ab);
    bf16* qbuf  = (bf16*)(ws + off_q);
    bf16* kbuf  = (bf16*)(ws + off_k);
    bf16* vbuf  = (bf16*)(ws + off_v);
    bf16* vt    = (bf16*)(ws + off_vt);
    bf16* obuf  = (bf16*)(ws + off_o);
    bf16* xt    = (bf16*)(ws + off_xt);
    bf16* wqkv  = (bf16*)(ws + off_wqkv);
    float* alf  = (float*)(ws + off_al);
    float* bef  = (float*)(ws + off_be);
    bf16* attn  = (bf16*)(ws + off_attn);
    const int* idxs = (const int*)d_in[26];

    k_detect<<<1, 64, 0, stream>>>((const unsigned*)d_in[0], flag);

    PtrArgs pa;
    for (int i = 0; i < 26; ++i) pa.p[i] = d_in[i];
    k_prep<<<dim3(288, 3), 256, 0, stream>>>(pa, wqkv, alf, bef, mb, flag);

    // tensors still needed in bf16: dwconv params, W1/W2/b2v (softmax), outproj params
    const int cidx[11] = {13, 14, 15, 16, 17, 19, 20, 21, 22, 23, 24};
    ConvArgs ca;
    for (int i = 0; i < 11; ++i) {
        ca.src[i] = d_in[cidx[i]];
        ca.dstoff[i] = p_off[cidx[i]];
        ca.n[i] = in_sizes[cidx[i]];
    }
    k_convb_all<<<dim3(64, 11), 256, 0, stream>>>(ca, ws, flag);

    bf16 *Wvl = Pb[13], *bvl = Pb[14], *vls = Pb[15], *vlb = Pb[16],
         *W1 = Pb[17], *W2 = Pb[19], *b2v = Pb[20],
         *Wp = Pb[21], *bp = Pb[22], *ps = Pb[23], *pb = Pb[24];

    k_xt<<<dim3(25, 12, 8), 256, 0, stream>>>(d_in[0], xt, flag);
    k_abfull<<<dim3(392), 256, 0, stream>>>(mb, idxs, abfull);

    k_proj_m<<<dim3(7, 12, 8), 256, 0, stream>>>(xt, wqkv, alf, bef, qbuf, kbuf, vbuf);
    k_vt<<<dim3(25, 32, 8), 256, 0, stream>>>(vbuf, vt);

    for (int bi0 = 0; bi0 < Bn; bi0 += GB) {
        k_logits_raw<<<dim3(7, 7, GB * 8), 256, 0, stream>>>(qbuf, kbuf, attn, bi0);
        k_softmax_mix<<<dim3(Nn, GB), 256, 0, stream>>>(attn, abfull, W1, W2, b2v);
        k_pv_m<<<dim3(13, 1, GB * 8), 256, 0, stream>>>(attn, vt, obuf, bi0);
    }

    k_dwconv_add<<<dim3(1, Nn / 2, 8), 256, 0, stream>>>(vbuf, Wvl, bvl, vls, vlb, obuf);
    k_outproj_m<<<dim3(7, 6, 8), 256, 0, stream>>>(Wp, obuf, bp, ps, pb, d_out, flag);
}

// Round 9
// 238.495 us; speedup vs baseline: 1.5040x; 1.1577x over previous
//
#include <hip/hip_runtime.h>
#include <hip/hip_bf16.h>

typedef __hip_bfloat16 bf16;
typedef __attribute__((ext_vector_type(8))) short short8v;
typedef __attribute__((ext_vector_type(4))) short short4v;
typedef __attribute__((ext_vector_type(4))) float f32x4;
typedef __attribute__((ext_vector_type(2))) float f32x2;

__device__ __forceinline__ float b2f(bf16 v){ return __bfloat162float(v); }
__device__ __forceinline__ bf16  f2b(float v){ return __float2bfloat16(v); }
__device__ __forceinline__ float su2f(short s){
    unsigned short us = (unsigned short)s;
    return __bfloat162float(*reinterpret_cast<bf16*>(&us));
}
__device__ __forceinline__ float ldf(const void* t, size_t i, int isb){
    return isb ? b2f(((const bf16*)t)[i]) : ((const float*)t)[i];
}

constexpr int Bn = 8, CIN = 384, RESn = 28, Nn = 784, DHn = 1024;
constexpr int AST = 800;   // padded attn/vt K-stride (25*32)

// ---------------------------------------------------- async global->LDS 16B
__device__ __forceinline__ void gload16(const void* g, void* l)
{
    __builtin_amdgcn_global_load_lds(
        (const __attribute__((address_space(1))) void*)g,
        (__attribute__((address_space(3))) void*)l, 16, 0, 0);
}

// -------------------------------------------------- dtype detector (1 thread)
__global__ void k_detect(const unsigned* __restrict__ xw, int* __restrict__ flag)
{
    if (blockIdx.x == 0 && threadIdx.x == 0) {
        int cnt = 0;
        for (int i = 0; i < 256; ++i) {
            unsigned lo = xw[i] & 0xFFFFu;
            int e = (int)((lo >> 7) & 0xFF);
            if (e >= 112 && e <= 132) ++cnt;
        }
        *flag = (cnt >= 128) ? 1 : 0;
    }
}

// -- fused prep: wpack | affine | mixbias | dw-weight transpose (reads d_in raw)
struct PtrArgs { const void* p[26]; };
__global__ __launch_bounds__(256) void k_prep(PtrArgs a, bf16* __restrict__ Wqkv,
                                              float* __restrict__ al, float* __restrict__ be,
                                              float* __restrict__ mb, bf16* __restrict__ Wvlt,
                                              const int* __restrict__ flag)
{
    const int isb = *flag;
    const int tid = threadIdx.x;
    const int role = blockIdx.y;
    if (role == 0) {
        int stride = gridDim.x * 256;
        for (int e = blockIdx.x * 256 + tid; e < 1536 * 384; e += stride) {
            int co = e / 384, k = e % 384;
            const void* src; int lc;
            if (co < 256)      { src = a.p[1]; lc = co; }
            else if (co < 512) { src = a.p[5]; lc = co - 256; }
            else               { src = a.p[9]; lc = co - 512; }
            Wqkv[e] = f2b(ldf(src, (size_t)lc * 384 + k, isb));
        }
    } else if (role == 1) {
        int co = blockIdx.x * 256 + tid;
        if (co < 1536) {
            const void *b_, *s_, *h_; int lc;
            if (co < 256)      { b_ = a.p[2];  s_ = a.p[3];  h_ = a.p[4];  lc = co; }
            else if (co < 512) { b_ = a.p[6];  s_ = a.p[7];  h_ = a.p[8];  lc = co - 256; }
            else               { b_ = a.p[10]; s_ = a.p[11]; h_ = a.p[12]; lc = co - 512; }
            float aa = ldf(s_, lc, isb);
            al[co] = aa;
            be[co] = ldf(b_, lc, isb) * aa + ldf(h_, lc, isb);
        }
    } else if (role == 2) {
        int i = blockIdx.x * 256 + tid;
        if (i < 8 * Nn) {
            int g = i / Nn, p = i % Nn;
            float acc = ldf(a.p[18], g, isb);
            #pragma unroll
            for (int h = 0; h < 8; ++h)
                acc += ldf(a.p[17], g * 8 + h, isb) * ldf(a.p[25], (size_t)h * Nn + p, isb);
            mb[i] = acc;
        }
    } else {
        int e = blockIdx.x * 256 + tid;   // Wvl [1024][9] -> Wvlt [9][1024]
        if (e < 1024 * 9) {
            int c = e / 9, tap = e % 9;
            Wvlt[tap * 1024 + c] = f2b(ldf(a.p[13], e, isb));
        }
    }
}

// ------------------------------------- convert needed tensors -> bf16
struct ConvArgs { const void* src[10]; unsigned long long dstoff[10]; int n[10]; };
__global__ void k_convb_all(ConvArgs a, char* __restrict__ ws, const int* __restrict__ flag)
{
    int i = blockIdx.y;
    int n = a.n[i];
    const void* s = a.src[i];
    bf16* d = (bf16*)(ws + a.dstoff[i]);
    int isb = *flag;
    int stride = gridDim.x * blockDim.x;
    for (int t = blockIdx.x * blockDim.x + threadIdx.x; t < n; t += stride)
        d[t] = isb ? ((const bf16*)s)[t] : f2b(((const float*)s)[t]);
}

// ------------------- expand mb through idx: abfull[g][n][m] (b-independent)
__global__ __launch_bounds__(256) void k_abfull(
    const float* __restrict__ mb, const int* __restrict__ idxs,
    bf16* __restrict__ abfull)
{
    __shared__ float mbs[8][Nn];
    const int tid = threadIdx.x;
    for (int i = tid; i < 8 * Nn; i += 256) ((float*)mbs)[i] = mb[i];
    __syncthreads();
    const int nstart = blockIdx.x * 2;
    for (int n = nstart; n < nstart + 2; ++n) {
        for (int m = tid; m < Nn; m += 256) {
            int id = idxs[(size_t)n * Nn + m];
            #pragma unroll
            for (int g = 0; g < 8; ++g)
                abfull[((size_t)g * Nn + n) * AST + m] = f2b(mbs[g][id]);
        }
    }
}

// ------------- x transpose + inline convert: [b][384][784] -> [b][784][384]
__global__ __launch_bounds__(256) void k_xt(const void* __restrict__ xr, bf16* __restrict__ xt,
                                            const int* __restrict__ flag)
{
    const int isb = *flag;
    __shared__ bf16 t[32][33];
    int b = blockIdx.z, n0 = blockIdx.x * 32, c0 = blockIdx.y * 32;
    int tid = threadIdx.x;
    for (int i = tid; i < 1024; i += 256) {
        int r = i >> 5, c = i & 31;
        int n = n0 + c;
        t[r][c] = (n < Nn) ? f2b(ldf(xr, ((size_t)b * CIN + c0 + r) * Nn + n, isb)) : f2b(0.f);
    }
    __syncthreads();
    for (int i = tid; i < 1024; i += 256) {
        int r = i >> 5, c = i & 31;
        int n = n0 + r;
        if (n < Nn) xt[((size_t)b * Nn + n) * CIN + c0 + c] = t[c][r];
    }
}

// --------------------- v transpose: [n][c] -> [c][n] (stride AST, zero-padded)
__global__ __launch_bounds__(256) void k_vt(const bf16* __restrict__ vbuf, bf16* __restrict__ vt)
{
    __shared__ bf16 t[32][33];
    int b = blockIdx.z, n0 = blockIdx.x * 32, c0 = blockIdx.y * 32;
    int tid = threadIdx.x;
    for (int i = tid; i < 1024; i += 256) {
        int r = i >> 5, c = i & 31;
        int n = n0 + r;
        t[r][c] = (n < Nn) ? vbuf[((size_t)b * Nn + n) * DHn + c0 + c] : f2b(0.f);
    }
    __syncthreads();
    for (int i = tid; i < 1024; i += 256) {
        int r = i >> 5, c = i & 31;
        int n = n0 + c;   // n < 800 always (25*32 grid)
        vt[((size_t)b * DHn + c0 + r) * AST + n] = t[c][r];
    }
}

// ------------------- generic MFMA core: tile (MI*32) x 128, BK=32, gload_lds
template<int MI>
__device__ __forceinline__ void gemm_core(
    const bf16* __restrict__ A, int lda, int rowsA, int arow0,
    const bf16* __restrict__ B, int ldb, int rowsB, int brow0,
    int K, short* ldsA, short* ldsB, f32x4 (&acc)[MI][4])
{
    const int tid  = threadIdx.x;
    const int lane = tid & 63;
    const int wm   = tid >> 7, wn = (tid >> 6) & 1;
    const int rsub = ((tid >> 6) << 4) | (tid & 15);
    const int q    = (tid >> 4) & 3;
    const int wbase = tid & 192;
    const short8v* A8 = (const short8v*)ldsA;
    const short8v* B8 = (const short8v*)ldsB;

    for (int k0 = 0; k0 < K; k0 += 32) {
        __syncthreads();
        #pragma unroll
        for (int c = 0; c < MI / 2; ++c) {
            int row = arow0 + c * 64 + rsub; row = row < rowsA ? row : rowsA - 1;
            gload16((const short*)A + (size_t)row * lda + k0 + q * 8,
                    ldsA + (size_t)(c * 256 + wbase) * 8);
        }
        #pragma unroll
        for (int c = 0; c < 2; ++c) {
            int row = brow0 + c * 64 + rsub; row = row < rowsB ? row : rowsB - 1;
            gload16((const short*)B + (size_t)row * ldb + k0 + q * 8,
                    ldsB + (size_t)(c * 256 + wbase) * 8);
        }
        __syncthreads();
        short8v a[MI], bb[4];
        #pragma unroll
        for (int i = 0; i < MI; ++i) a[i] = A8[(wm * MI + i) * 64 + lane];
        #pragma unroll
        for (int j = 0; j < 4; ++j) bb[j] = B8[(wn * 4 + j) * 64 + lane];
        #pragma unroll
        for (int i = 0; i < MI; ++i)
            #pragma unroll
            for (int j = 0; j < 4; ++j)
                acc[i][j] = __builtin_amdgcn_mfma_f32_16x16x32_bf16(a[i], bb[j], acc[i][j], 0, 0, 0);
    }
}

#define EPI_COORDS(MI)                                      \
    const int tid  = threadIdx.x;                           \
    const int lane = tid & 63;                              \
    const int wm   = tid >> 7, wn = (tid >> 6) & 1;         \
    const int rq   = lane >> 4, cl = lane & 15; (void)rq;

// --------------------------------------------- q/k/v projection + BN (MFMA)
__global__ __launch_bounds__(256) void k_proj_m(
    const bf16* __restrict__ xt, const bf16* __restrict__ Wqkv,
    const float* __restrict__ al, const float* __restrict__ be,
    bf16* __restrict__ qbuf, bf16* __restrict__ kbuf, bf16* __restrict__ vbuf)
{
    __shared__ short ldsA[4096], ldsB[4096];
    const int n0 = blockIdx.x * 128, co0 = blockIdx.y * 128;
    const int b = blockIdx.z;
    f32x4 acc[4][4] = {};
    gemm_core<4>(xt + (size_t)b * Nn * CIN, CIN, Nn, n0,
                 Wqkv, CIN, 1536, co0, CIN, ldsA, ldsB, acc);
    EPI_COORDS(4)
    #pragma unroll
    for (int i = 0; i < 4; ++i)
        #pragma unroll
        for (int j = 0; j < 4; ++j) {
            int co = co0 + (wn * 4 + j) * 16 + cl;
            float a_ = al[co], bb_ = be[co];
            int nb = n0 + (wm * 4 + i) * 16 + rq * 4;
            #pragma unroll
            for (int r = 0; r < 4; ++r) {
                int n = nb + r;
                if (n >= Nn) continue;
                float y = a_ * acc[i][j][r] + bb_;
                if (co < 256)      qbuf[((size_t)b * Nn + n) * 256 + co]       = f2b(y);
                else if (co < 512) kbuf[((size_t)b * Nn + n) * 256 + (co-256)] = f2b(y);
                else               vbuf[((size_t)b * Nn + n) * DHn + (co-512)] = f2b(y);
            }
        }
}

// ----------------------- raw per-head logits: qk[h][n][m], K=32 (no mix/bias)
__global__ __launch_bounds__(256) void k_logits_raw(
    const bf16* __restrict__ qbuf, const bf16* __restrict__ kbuf,
    bf16* __restrict__ attn, int bi0)
{
    __shared__ short ldsA[4096], ldsB[4096];
    const int n0 = blockIdx.x * 128, m0 = blockIdx.y * 128;
    const int z = blockIdx.z, h = z & 7, bloc = z >> 3, b = bi0 + bloc;
    f32x4 acc[4][4] = {};
    gemm_core<4>(qbuf + (size_t)b * Nn * 256 + h * 32, 256, Nn, n0,
                 kbuf + (size_t)b * Nn * 256 + h * 32, 256, Nn, m0,
                 32, ldsA, ldsB, acc);
    bf16* arow = attn + (size_t)(bloc * 8 + h) * Nn * AST;
    EPI_COORDS(4)
    #pragma unroll
    for (int i = 0; i < 4; ++i)
        #pragma unroll
        for (int j = 0; j < 4; ++j) {
            int m = m0 + (wn * 4 + j) * 16 + cl;
            if (m >= Nn) continue;
            int nb = n0 + (wm * 4 + i) * 16 + rq * 4;
            #pragma unroll
            for (int r = 0; r < 4; ++r) {
                int n = nb + r;
                if (n < Nn) arow[(size_t)n * AST + m] = f2b(acc[i][j][r]);
            }
        }
}

// --- fused: th1 mix (+abfull) + softmax (no-max, clamp) + th2 mix, registers
__global__ __launch_bounds__(256) void k_softmax_mix(
    bf16* __restrict__ attn_all, const bf16* __restrict__ abfull,
    const bf16* __restrict__ W1, const bf16* __restrict__ W2, const bf16* __restrict__ b2v)
{
    const int n = blockIdx.x, bloc = blockIdx.y;
    const int tid = threadIdx.x;
    bf16* base = attn_all + (size_t)bloc * 8 * Nn * AST;
    __shared__ float w1s[64], w2s[64], b2sh[8], lis[8], wred[4][8];
    if (tid < 64) { w1s[tid] = b2f(W1[tid]) * 0.17677669529663687f; w2s[tid] = b2f(W2[tid]); }
    if (tid < 8)  b2sh[tid] = b2f(b2v[tid]);
    __syncthreads();

    const bool live = tid < 196;
    const int m0 = (live ? tid : 195) * 4;

    f32x2 raw2[8][2];
    #pragma unroll
    for (int h = 0; h < 8; ++h) {
        short4v v = *(const short4v*)(base + ((size_t)h * Nn + n) * AST + m0);
        raw2[h][0] = f32x2{su2f(v[0]), su2f(v[1])};
        raw2[h][1] = f32x2{su2f(v[2]), su2f(v[3])};
    }

    float out[8][4];
    #pragma unroll
    for (int g = 0; g < 8; ++g) {
        short4v bv = *(const short4v*)(abfull + ((size_t)g * Nn + n) * AST + m0);
        f32x2 a0 = {su2f(bv[0]), su2f(bv[1])};
        f32x2 a1 = {su2f(bv[2]), su2f(bv[3])};
        #pragma unroll
        for (int h = 0; h < 8; ++h) {
            float w = w1s[g * 8 + h];
            f32x2 wv = {w, w};
            a0 += raw2[h][0] * wv;
            a1 += raw2[h][1] * wv;
        }
        out[g][0] = __expf(fminf(a0[0], 60.f));
        out[g][1] = __expf(fminf(a0[1], 60.f));
        out[g][2] = __expf(fminf(a1[0], 60.f));
        out[g][3] = __expf(fminf(a1[1], 60.f));
        float s = live ? (out[g][0] + out[g][1]) + (out[g][2] + out[g][3]) : 0.f;
        #pragma unroll
        for (int sh = 32; sh > 0; sh >>= 1) s += __shfl_xor(s, sh, 64);
        if ((tid & 63) == 0) wred[tid >> 6][g] = s;
    }
    __syncthreads();
    if (tid < 8)
        lis[tid] = 1.f / (wred[0][tid] + wred[1][tid] + wred[2][tid] + wred[3][tid]);
    __syncthreads();

    f32x2 p2[8][2];
    #pragma unroll
    for (int h = 0; h < 8; ++h) {
        float lh = lis[h];
        p2[h][0] = f32x2{out[h][0] * lh, out[h][1] * lh};
        p2[h][1] = f32x2{out[h][2] * lh, out[h][3] * lh};
    }
    if (live) {
        #pragma unroll
        for (int g = 0; g < 8; ++g) {
            f32x2 acc0 = {b2sh[g], b2sh[g]};
            f32x2 acc1 = acc0;
            #pragma unroll
            for (int h = 0; h < 8; ++h) {
                float w = w2s[g * 8 + h];
                f32x2 wv = {w, w};
                acc0 += p2[h][0] * wv;
                acc1 += p2[h][1] * wv;
            }
            short4v sv;
            bf16 b0 = f2b(acc0[0]); sv[0] = *reinterpret_cast<short*>(&b0);
            bf16 b1 = f2b(acc0[1]); sv[1] = *reinterpret_cast<short*>(&b1);
            bf16 b2 = f2b(acc1[0]); sv[2] = *reinterpret_cast<short*>(&b2);
            bf16 b3 = f2b(acc1[1]); sv[3] = *reinterpret_cast<short*>(&b3);
            *(short4v*)(base + ((size_t)g * Nn + n) * AST + m0) = sv;
        }
    }
}

// ------------------------------------------------ PV: obuf[b][n][c] = P2 · v
__global__ __launch_bounds__(256) void k_pv_m(
    const bf16* __restrict__ attn, const bf16* __restrict__ vt,
    bf16* __restrict__ obuf, int bi0)
{
    __shared__ short ldsA[2048], ldsB[4096];
    const int n0 = blockIdx.x * 64;
    const int z = blockIdx.z, g = z & 7, bloc = z >> 3, b = bi0 + bloc;
    f32x4 acc[2][4] = {};
    gemm_core<2>(attn + (size_t)(bloc * 8 + g) * Nn * AST, AST, Nn, n0,
                 vt + ((size_t)b * DHn + g * 128) * AST, AST, 128, 0,
                 AST, ldsA, ldsB, acc);
    bf16* ob = obuf + (size_t)b * Nn * DHn + g * 128;
    EPI_COORDS(2)
    #pragma unroll
    for (int i = 0; i < 2; ++i)
        #pragma unroll
        for (int j = 0; j < 4; ++j) {
            int d = (wn * 4 + j) * 16 + cl;
            int nb = n0 + (wm * 2 + i) * 16 + rq * 4;
            #pragma unroll
            for (int r = 0; r < 4; ++r) {
                int n = nb + r;
                if (n < Nn) ob[(size_t)n * DHn + d] = f2b(acc[i][j][r]);
            }
        }
}

// ---- depthwise conv+BN, ADDS into obuf (o += vl), fully vectorized weights
__global__ __launch_bounds__(256) void k_dwconv_add(
    const bf16* __restrict__ vbuf, const bf16* __restrict__ Wvlt,
    const bf16* __restrict__ bvl, const bf16* __restrict__ vls, const bf16* __restrict__ vlb,
    bf16* __restrict__ obuf)
{
    const int t = threadIdx.x;
    const int n = blockIdx.y * 2 + (t >> 7);
    const int bi = blockIdx.z;
    const int c0 = (t & 127) * 8;
    const int h = n / RESn, w = n % RESn;
    float acc[8] = {};
    #pragma unroll
    for (int dh = -1; dh <= 1; ++dh)
        #pragma unroll
        for (int dw = -1; dw <= 1; ++dw) {
            int hh = h + dh, ww = w + dw;
            if (hh < 0 || hh >= RESn || ww < 0 || ww >= RESn) continue;
            int widx = (dh + 1) * 3 + (dw + 1);
            short8v wv = *(const short8v*)&Wvlt[widx * 1024 + c0];
            short8v v  = *(const short8v*)&vbuf[((size_t)bi * Nn + hh * RESn + ww) * DHn + c0];
            #pragma unroll
            for (int u = 0; u < 8; ++u)
                acc[u] += su2f(wv[u]) * su2f(v[u]);
        }
    short8v bv = *(const short8v*)&bvl[c0];
    short8v sv = *(const short8v*)&vls[c0];
    short8v hv = *(const short8v*)&vlb[c0];
    size_t off = ((size_t)bi * Nn + n) * DHn + c0;
    short8v ov = *(short8v*)&obuf[off];
    short8v res;
    #pragma unroll
    for (int u = 0; u < 8; ++u) {
        float vl = su2f(sv[u]) * (acc[u] + su2f(bv[u])) + su2f(hv[u]);
        bf16 bo = f2b(su2f(ov[u]) + vl);
        res[u] = *reinterpret_cast<short*>(&bo);
    }
    *(short8v*)&obuf[off] = res;
}

// --------------------------------------------- output projection + BN (MFMA)
__global__ __launch_bounds__(256) void k_outproj_m(
    const bf16* __restrict__ Wp, const bf16* __restrict__ obuf,
    const bf16* __restrict__ bp, const bf16* __restrict__ ps, const bf16* __restrict__ pb,
    void* __restrict__ outv, const int* __restrict__ flag)
{
    __shared__ short ldsA[2048], ldsB[4096];
    const int n0 = blockIdx.x * 128, oc0 = blockIdx.y * 64;
    const int b = blockIdx.z;
    f32x4 acc[2][4] = {};
    gemm_core<2>(Wp, DHn, 384, oc0,
                 obuf + (size_t)b * Nn * DHn, DHn, Nn, n0,
                 DHn, ldsA, ldsB, acc);
    const int isb = *flag;
    EPI_COORDS(2)
    #pragma unroll
    for (int i = 0; i < 2; ++i)
        #pragma unroll
        for (int j = 0; j < 4; ++j) {
            int n = n0 + (wn * 4 + j) * 16 + cl;
            if (n >= Nn) continue;
            int ocb = oc0 + (wm * 2 + i) * 16 + rq * 4;
            #pragma unroll
            for (int r = 0; r < 4; ++r) {
                int oc = ocb + r;
                float a_ = b2f(ps[oc]);
                float be_ = b2f(bp[oc]) * a_ + b2f(pb[oc]);
                float y = a_ * acc[i][j][r] + be_;
                size_t idx = ((size_t)b * CIN + oc) * Nn + n;
                if (isb) ((bf16*)outv)[idx] = f2b(y);
                else     ((float*)outv)[idx] = y;
            }
        }
}

extern "C" void kernel_launch(void* const* d_in, const int* in_sizes, int n_in,
                              void* d_out, int out_size, void* d_ws, size_t ws_size,
                              hipStream_t stream)
{
    char* ws = (char*)d_ws;
    auto align256 = [](size_t v) { return (v + 255) & ~(size_t)255; };

    size_t off = 0;
    size_t off_flag = off;            off = align256(off + 4);
    size_t p_off[26];
    for (int i = 0; i < 26; ++i) { p_off[i] = off; off = align256(off + (size_t)in_sizes[i] * 2); }
    size_t off_mb   = off; off = align256(off + (size_t)8 * Nn * 4);
    size_t off_ab   = off; off = align256(off + (size_t)8 * Nn * AST * 2);
    size_t off_q    = off; off = align256(off + (size_t)Bn * Nn * 256 * 2);
    size_t off_k    = off; off = align256(off + (size_t)Bn * Nn * 256 * 2);
    size_t off_v    = off; off = align256(off + (size_t)Bn * Nn * DHn * 2);
    size_t off_vt   = off; off = align256(off + (size_t)Bn * DHn * AST * 2);
    size_t off_o    = off; off = align256(off + (size_t)Bn * Nn * DHn * 2);
    size_t off_xt   = off; off = align256(off + (size_t)Bn * Nn * CIN * 2);
    size_t off_wqkv = off; off = align256(off + (size_t)1536 * CIN * 2);
    size_t off_al   = off; off = align256(off + (size_t)1536 * 4);
    size_t off_be   = off; off = align256(off + (size_t)1536 * 4);
    size_t off_wvlt = off; off = align256(off + (size_t)9 * 1024 * 2);
    size_t base = off;

    const size_t attn_per_b = (size_t)8 * Nn * AST * 2;
    int GB = 0;
    const int cand[4] = {8, 4, 2, 1};
    for (int ci = 0; ci < 4; ++ci) {
        if (base + (size_t)cand[ci] * attn_per_b + 512 <= ws_size) { GB = cand[ci]; break; }
    }
    if (!GB) return; // ws too small -> zeros out (diagnostic absmax ~17.4)

    size_t off_attn = base;

    int*  flag = (int*)(ws + off_flag);
    bf16* Pb[26];
    for (int i = 0; i < 26; ++i) Pb[i] = (bf16*)(ws + p_off[i]);
    float* mb    = (float*)(ws + off_mb);
    bf16* abfull = (bf16*)(ws + off_ab);
    bf16* qbuf  = (bf16*)(ws + off_q);
    bf16* kbuf  = (bf16*)(ws + off_k);
    bf16* vbuf  = (bf16*)(ws + off_v);
    bf16* vt    = (bf16*)(ws + off_vt);
    bf16* obuf  = (bf16*)(ws + off_o);
    bf16* xt    = (bf16*)(ws + off_xt);
    bf16* wqkv  = (bf16*)(ws + off_wqkv);
    float* alf  = (float*)(ws + off_al);
    float* bef  = (float*)(ws + off_be);
    bf16* wvlt  = (bf16*)(ws + off_wvlt);
    bf16* attn  = (bf16*)(ws + off_attn);
    const int* idxs = (const int*)d_in[26];

    k_detect<<<1, 64, 0, stream>>>((const unsigned*)d_in[0], flag);

    PtrArgs pa;
    for (int i = 0; i < 26; ++i) pa.p[i] = d_in[i];
    k_prep<<<dim3(288, 4), 256, 0, stream>>>(pa, wqkv, alf, bef, mb, wvlt, flag);

    // tensors still needed in bf16: dwconv affine, W1/W2/b2v (softmax), outproj params
    const int cidx[10] = {14, 15, 16, 17, 19, 20, 21, 22, 23, 24};
    ConvArgs ca;
    for (int i = 0; i < 10; ++i) {
        ca.src[i] = d_in[cidx[i]];
        ca.dstoff[i] = p_off[cidx[i]];
        ca.n[i] = in_sizes[cidx[i]];
    }
    k_convb_all<<<dim3(64, 10), 256, 0, stream>>>(ca, ws, flag);

    bf16 *bvl = Pb[14], *vls = Pb[15], *vlb = Pb[16],
         *W1 = Pb[17], *W2 = Pb[19], *b2v = Pb[20],
         *Wp = Pb[21], *bp = Pb[22], *ps = Pb[23], *pb = Pb[24];

    k_xt<<<dim3(25, 12, 8), 256, 0, stream>>>(d_in[0], xt, flag);
    k_abfull<<<dim3(392), 256, 0, stream>>>(mb, idxs, abfull);

    k_proj_m<<<dim3(7, 12, 8), 256, 0, stream>>>(xt, wqkv, alf, bef, qbuf, kbuf, vbuf);
    k_vt<<<dim3(25, 32, 8), 256, 0, stream>>>(vbuf, vt);

    for (int bi0 = 0; bi0 < Bn; bi0 += GB) {
        k_logits_raw<<<dim3(7, 7, GB * 8), 256, 0, stream>>>(qbuf, kbuf, attn, bi0);
        k_softmax_mix<<<dim3(Nn, GB), 256, 0, stream>>>(attn, abfull, W1, W2, b2v);
        k_pv_m<<<dim3(13, 1, GB * 8), 256, 0, stream>>>(attn, vt, obuf, bi0);
    }

    k_dwconv_add<<<dim3(1, Nn / 2, 8), 256, 0, stream>>>(vbuf, wvlt, bvl, vls, vlb, obuf);
    k_outproj_m<<<dim3(7, 6, 8), 256, 0, stream>>>(Wp, obuf, bp, ps, pb, d_out, flag);
}